// Round 5
// baseline (334.990 us; speedup 1.0000x reference)
//
#include <hip/hip_runtime.h>

#define BB 32
#define TT 512
#define FF 128
#define HID 256
#define TP 1024

typedef __attribute__((ext_vector_type(8))) short s16x8;
typedef __attribute__((ext_vector_type(8))) unsigned short u16x8;
typedef __attribute__((ext_vector_type(4))) unsigned short u16x4;
typedef __attribute__((ext_vector_type(4))) float f32x4;

static __device__ __forceinline__ unsigned short f2bf(float f) {
    unsigned u = __builtin_bit_cast(unsigned, f);
    u = (u + 0x7FFFu + ((u >> 16) & 1u)) >> 16;
    return (unsigned short)u;
}
static __device__ __forceinline__ float bf2f(unsigned short b) {
    return __builtin_bit_cast(float, ((unsigned)b) << 16);
}

// ---------------------------------------------------------------------------
// transpose-convert: src fp32 [b][128][512] -> dst bf16 [b][512][128].
// ---------------------------------------------------------------------------
__global__ __launch_bounds__(256) void t2bf_kernel(
    const float* __restrict__ src, unsigned short* __restrict__ dst)
{
    int t0 = blockIdx.x * 32, c0 = blockIdx.y * 32, b = blockIdx.z;
    __shared__ float tile[32][33];
    int tid = threadIdx.x;
    for (int l = tid; l < 1024; l += 256) {
        int c = l >> 5, t = l & 31;
        tile[c][t] = src[((size_t)b * FF + c0 + c) * TT + t0 + t];
    }
    __syncthreads();
    for (int l = tid; l < 1024; l += 256) {
        int t = l >> 5, c = l & 31;
        dst[((size_t)b * TT + t0 + t) * FF + c0 + c] = f2bf(tile[c][t]);
    }
}

// ---------------------------------------------------------------------------
// QKV weight prep: out bf16 [6][128][128]; planes 0,3 (wq_a, wq_b) pre-scaled.
// ---------------------------------------------------------------------------
__global__ __launch_bounds__(256) void prep_qkvw_kernel(
    const float* __restrict__ wqa, const float* __restrict__ wka,
    const float* __restrict__ wva, const float* __restrict__ wqb,
    const float* __restrict__ wkb, const float* __restrict__ wvb,
    unsigned short* __restrict__ out)
{
    int idx = blockIdx.x * 256 + threadIdx.x;
    if (idx >= 6 * 16384) return;
    int p = idx >> 14, rc = idx & 16383;
    const float* srcs[6] = {wqa, wka, wva, wqb, wkb, wvb};
    float v = srcs[p][rc];
    if (p == 0 || p == 3) v *= 0.088388347648318447f;
    out[idx] = f2bf(v);
}

// ---------------------------------------------------------------------------
// QKV projection via MFMA.  grid (16, 32), block 256 = 4 waves.
// ---------------------------------------------------------------------------
__global__ __launch_bounds__(256) void proj_mfma_kernel(
    const unsigned short* __restrict__ xq_src, long long xq_bs,
    const unsigned short* __restrict__ xkv_src, long long xkv_bs,
    const unsigned short* __restrict__ w3,
    const float* __restrict__ bq, const float* __restrict__ bk,
    const float* __restrict__ bv,
    unsigned short* __restrict__ Qo, unsigned short* __restrict__ Ko,
    unsigned short* __restrict__ Vt)
{
    int t0 = blockIdx.x * 32, b = blockIdx.y;
    __shared__ __align__(16) unsigned short xsq[32 * 136];
    __shared__ __align__(16) unsigned short xskv[32 * 136];
    int tid = threadIdx.x;
    int wid = tid >> 6, lane = tid & 63;
    int n = lane & 15, g = lane >> 4;
    int tsub = (wid & 1) * 16, fh = (wid >> 1) * 64;

    for (int l = tid; l < 512; l += 256) {
        int r = l >> 4, cc = l & 15;
        *(u16x8*)&xsq[r * 136 + cc * 8] =
            *(const u16x8*)&xq_src[xq_bs * b + (size_t)(t0 + r) * FF + cc * 8];
        *(u16x8*)&xskv[r * 136 + cc * 8] =
            *(const u16x8*)&xkv_src[xkv_bs * b + (size_t)(t0 + r) * FF + cc * 8];
    }
    __syncthreads();

    f32x4 acc[3][4];
#pragma unroll
    for (int p = 0; p < 3; ++p)
#pragma unroll
        for (int i = 0; i < 4; ++i) acc[p][i] = (f32x4){0.f, 0.f, 0.f, 0.f};

#pragma unroll
    for (int kk = 0; kk < 4; ++kk) {
        s16x8 bxq = *(const s16x8*)&xsq[(tsub + n) * 136 + kk * 32 + g * 8];
        s16x8 bxkv = *(const s16x8*)&xskv[(tsub + n) * 136 + kk * 32 + g * 8];
#pragma unroll
        for (int i = 0; i < 4; ++i) {
            const unsigned short* wb = &w3[(size_t)(fh + i * 16 + n) * 128 + kk * 32 + g * 8];
            s16x8 a0 = *(const s16x8*)&wb[0];
            s16x8 a1 = *(const s16x8*)&wb[16384];
            s16x8 a2 = *(const s16x8*)&wb[32768];
            acc[0][i] = __builtin_amdgcn_mfma_f32_16x16x32_bf16(a0, bxq, acc[0][i], 0, 0, 0);
            acc[1][i] = __builtin_amdgcn_mfma_f32_16x16x32_bf16(a1, bxkv, acc[1][i], 0, 0, 0);
            acc[2][i] = __builtin_amdgcn_mfma_f32_16x16x32_bf16(a2, bxkv, acc[2][i], 0, 0, 0);
        }
    }

    const float scale = 0.088388347648318447f;
    int t = t0 + tsub + n;
#pragma unroll
    for (int i = 0; i < 4; ++i) {
        int fb = fh + i * 16 + g * 4;
        u16x4 pk;
#pragma unroll
        for (int r = 0; r < 4; ++r) pk[r] = f2bf(acc[0][i][r] + bq[fb + r] * scale);
        *(u16x4*)&Qo[((size_t)b * TT + t) * FF + fb] = pk;
#pragma unroll
        for (int r = 0; r < 4; ++r) pk[r] = f2bf(acc[1][i][r] + bk[fb + r]);
        *(u16x4*)&Ko[((size_t)b * TT + t) * FF + fb] = pk;
#pragma unroll
        for (int r = 0; r < 4; ++r)
            Vt[((size_t)b * FF + fb + r) * TT + t] = f2bf(acc[2][i][r] + bv[fb + r]);
    }
}

// ---------------------------------------------------------------------------
// Flash attention via MFMA.  grid (8, 32), block 256 = 4 waves.
// ---------------------------------------------------------------------------
__global__ __launch_bounds__(256) void attn_mfma_kernel(
    const unsigned short* __restrict__ Qb, const unsigned short* __restrict__ Kb,
    const unsigned short* __restrict__ Vtb,
    const float* __restrict__ orig, long long bso, int cso, int tso,
    float* __restrict__ out_tf, unsigned short* __restrict__ out_x, int xoff)
{
    __shared__ __align__(16) unsigned short Ks[64 * 136];
    __shared__ __align__(16) unsigned short Vs[128 * 72];
    __shared__ __align__(16) unsigned short Ps[4 * 16 * 68];

    int t0 = blockIdx.x * 64, b = blockIdx.y;
    int tid = threadIdx.x;
    int wid = tid >> 6, lane = tid & 63;
    int n = lane & 15, g = lane >> 4;
    int q0 = t0 + wid * 16;
    unsigned short* Pw = &Ps[wid * 1088];

    s16x8 qf[4];
#pragma unroll
    for (int kk = 0; kk < 4; ++kk)
        qf[kk] = *(const s16x8*)&Qb[((size_t)b * TT + q0 + n) * FF + kk * 32 + g * 8];

    u16x8 kst[4], vst[4];
#pragma unroll
    for (int ii = 0; ii < 4; ++ii) {
        int l = tid + 256 * ii;
        kst[ii] = *(const u16x8*)&Kb[((size_t)b * TT + (l >> 4)) * FF + (l & 15) * 8];
        vst[ii] = *(const u16x8*)&Vtb[((size_t)b * FF + (l >> 3)) * TT + (l & 7) * 8];
    }

    f32x4 O[8];
#pragma unroll
    for (int ft = 0; ft < 8; ++ft) O[ft] = (f32x4){0.f, 0.f, 0.f, 0.f};
    float m[4] = {-1e30f, -1e30f, -1e30f, -1e30f};
    float lsum[4] = {0.f, 0.f, 0.f, 0.f};

    for (int it = 0; it < 8; ++it) {
        __syncthreads();
#pragma unroll
        for (int ii = 0; ii < 4; ++ii) {
            int l = tid + 256 * ii;
            *(u16x8*)&Ks[(l >> 4) * 136 + (l & 15) * 8] = kst[ii];
            *(u16x8*)&Vs[(l >> 3) * 72 + (l & 7) * 8] = vst[ii];
        }
        __syncthreads();
        if (it < 7) {
            int s0n = (it + 1) * 64;
#pragma unroll
            for (int ii = 0; ii < 4; ++ii) {
                int l = tid + 256 * ii;
                kst[ii] = *(const u16x8*)&Kb[((size_t)b * TT + s0n + (l >> 4)) * FF + (l & 15) * 8];
                vst[ii] = *(const u16x8*)&Vtb[((size_t)b * FF + (l >> 3)) * TT + s0n + (l & 7) * 8];
            }
        }

        f32x4 acc[4];
#pragma unroll
        for (int st = 0; st < 4; ++st) acc[st] = (f32x4){0.f, 0.f, 0.f, 0.f};
#pragma unroll
        for (int kk = 0; kk < 4; ++kk) {
#pragma unroll
            for (int st = 0; st < 4; ++st) {
                s16x8 kf = *(const s16x8*)&Ks[(st * 16 + n) * 136 + kk * 32 + g * 8];
                acc[st] = __builtin_amdgcn_mfma_f32_16x16x32_bf16(qf[kk], kf, acc[st], 0, 0, 0);
            }
        }

        float mnew[4], c[4], rs[4];
#pragma unroll
        for (int r = 0; r < 4; ++r) {
            float tm = fmaxf(fmaxf(acc[0][r], acc[1][r]), fmaxf(acc[2][r], acc[3][r]));
#pragma unroll
            for (int msk = 1; msk < 16; msk <<= 1) tm = fmaxf(tm, __shfl_xor(tm, msk));
            mnew[r] = fmaxf(m[r], tm);
            c[r] = __expf(m[r] - mnew[r]);
            m[r] = mnew[r];
            rs[r] = 0.f;
        }
#pragma unroll
        for (int st = 0; st < 4; ++st) {
#pragma unroll
            for (int r = 0; r < 4; ++r) {
                float p = __expf(acc[st][r] - mnew[r]);
                rs[r] += p;
                Pw[(g * 4 + r) * 68 + st * 16 + n] = f2bf(p);
            }
        }
#pragma unroll
        for (int r = 0; r < 4; ++r) {
#pragma unroll
            for (int msk = 1; msk < 16; msk <<= 1) rs[r] += __shfl_xor(rs[r], msk);
            lsum[r] = lsum[r] * c[r] + rs[r];
        }
#pragma unroll
        for (int ft = 0; ft < 8; ++ft) {
#pragma unroll
            for (int r = 0; r < 4; ++r) O[ft][r] *= c[r];
        }

#pragma unroll
        for (int ks = 0; ks < 2; ++ks) {
            s16x8 pf = *(const s16x8*)&Pw[n * 68 + ks * 32 + g * 8];
#pragma unroll
            for (int ft = 0; ft < 8; ++ft) {
                s16x8 vf = *(const s16x8*)&Vs[(ft * 16 + n) * 72 + ks * 32 + g * 8];
                O[ft] = __builtin_amdgcn_mfma_f32_16x16x32_bf16(pf, vf, O[ft], 0, 0, 0);
            }
        }
    }

    float rinv[4];
#pragma unroll
    for (int r = 0; r < 4; ++r) rinv[r] = 1.f / lsum[r];
#pragma unroll
    for (int ft = 0; ft < 8; ++ft) {
        int f = ft * 16 + n;
#pragma unroll
        for (int r = 0; r < 4; ++r) {
            int q = q0 + g * 4 + r;
            float val = O[ft][r] * rinv[r];
            float xv = orig[bso * b + (size_t)f * cso + (size_t)q * tso];
            float res = val * xv + xv;
            out_tf[((size_t)b * TT + q) * FF + f] = res;
            out_x[((size_t)b * TP + xoff + q) * FF + f] = f2bf(res);
        }
    }
}

// ---------------------------------------------------------------------------
// MMD partials per timepoint (fp32 exact).
// ---------------------------------------------------------------------------
__global__ __launch_bounds__(256) void mmd_kernel(
    const float* __restrict__ f1, const float* __restrict__ f2,
    float* __restrict__ partials)
{
    int t = blockIdx.x;
    __shared__ float v1[32][129], v2[32][129];
    __shared__ float red[256];
    int tid = threadIdx.x;
    for (int l = tid; l < 4096; l += 256) {
        int i = l >> 7, f = l & 127;
        v1[i][f] = f1[((size_t)i * TT + t) * FF + f];
        v2[i][f] = f2[((size_t)i * TT + t) * FF + f];
    }
    __syncthreads();
    float s = 0.f;
    for (int r = 0; r < 4; ++r) {
        int p = tid + 256 * r;
        int i = p >> 5, j = p & 31;
        float dxx = 0.f, dyy = 0.f, dxy = 0.f;
        for (int f = 0; f < 128; ++f) {
            float a = v1[i][f], b_ = v1[j][f], c = v2[i][f], d = v2[j][f];
            float e1 = a - b_, e2 = c - d, e3 = a - d;
            dxx += e1 * e1; dyy += e2 * e2; dxy += e3 * e3;
        }
        s += __expf(-0.5f * dxx) + __expf(-0.5f * dyy) - 2.f * __expf(-0.5f * dxy);
    }
    red[tid] = s;
    __syncthreads();
    for (int off = 128; off; off >>= 1) {
        if (tid < off) red[tid] += red[tid + off];
        __syncthreads();
    }
    if (tid == 0) partials[t] = red[0];
}

// ---------------------------------------------------------------------------
// TCN weight prep: w4[plane][o][c] bf16, planes 0..2 = conv taps, 3 = residual.
// ---------------------------------------------------------------------------
__global__ __launch_bounds__(256) void prep_w_kernel(
    const float* __restrict__ cw, const float* __restrict__ rw,
    unsigned short* __restrict__ out, int Cin)
{
    int idx = blockIdx.x * 256 + threadIdx.x;
    int total = 4 * 256 * Cin;
    if (idx >= total) return;
    int p = idx / (256 * Cin);
    int rem = idx - p * 256 * Cin;
    int o = rem / Cin, c = rem - o * Cin;
    float v = (p < 3) ? cw[(o * Cin + c) * 3 + p] : rw[o * Cin + c];
    out[idx] = f2bf(v);
}

// ---------------------------------------------------------------------------
// TCN layer via MFMA.  x bf16 [b][t][Cin]; w4 bf16 [4][256][Cin];
// out bf16 [b][t][256].  grid (8 t-tiles of 128, 4 o-tiles, 32 b), block 256
// (4 waves); wave tile 64o x 32t.  Staging is load-early/write-late (T14).
// do_pool: instead of writing h, reduce sum over t into pool_out partial
// slices [b][8 tslices][256 o] (deterministic, no atomics).
// ---------------------------------------------------------------------------
__global__ __launch_bounds__(256) void tcn_mfma_kernel(
    const unsigned short* __restrict__ x, int Cin, int d,
    const unsigned short* __restrict__ w4,
    const float* __restrict__ cb, const float* __restrict__ rb,
    unsigned short* __restrict__ out, float* __restrict__ pool_out, int do_pool)
{
    int t0 = blockIdx.x * 128, o0 = blockIdx.y * 64, b = blockIdx.z;
    __shared__ __align__(16) unsigned short xs[136 * 40];
    __shared__ float pool_s[4][64];
    int tid = threadIdx.x;
    int wid = tid >> 6, lane = tid & 63;
    int n = lane & 15, g = lane >> 4;
    int wt0 = wid * 32;
    int d2 = 2 * d;
    int nrow = 128 + d2;           // <= 136
    const unsigned short* xb = x + (size_t)b * TP * Cin;

    // staging geometry: element e = tid + 256*r, row = e>>2, gg = e&3
    int gg = tid & 3;
    int row0 = tid >> 2;           // 0..63   (always valid)
    int row1 = (tid + 256) >> 2;   // 64..127 (always valid)
    int row2 = (tid + 512) >> 2;   // 128..191 (valid iff < nrow)
    int tg0 = t0 - d2 + row0;
    int tg2 = t0 - d2 + row2;
    bool w2 = row2 < nrow;

    u16x8 st0, st1, st2;
    const u16x8 zz = {0, 0, 0, 0, 0, 0, 0, 0};
#define LDST(C0)                                                              \
    do {                                                                      \
        st0 = (tg0 >= 0) ? *(const u16x8*)&xb[(size_t)tg0 * Cin + (C0) + gg * 8] : zz; \
        st1 = *(const u16x8*)&xb[(size_t)(t0 - d2 + row1) * Cin + (C0) + gg * 8];      \
        st2 = w2 ? *(const u16x8*)&xb[(size_t)tg2 * Cin + (C0) + gg * 8] : zz; \
    } while (0)

    f32x4 accc[4][2], accr[4][2];
#pragma unroll
    for (int i = 0; i < 4; ++i)
#pragma unroll
        for (int j = 0; j < 2; ++j) {
            accc[i][j] = (f32x4){0.f, 0.f, 0.f, 0.f};
            accr[i][j] = (f32x4){0.f, 0.f, 0.f, 0.f};
        }

    LDST(0);
    for (int c0 = 0; c0 < Cin; c0 += 32) {
        __syncthreads();   // previous iter's LDS reads complete
        *(u16x8*)&xs[row0 * 40 + gg * 8] = st0;
        *(u16x8*)&xs[row1 * 40 + gg * 8] = st1;
        if (w2) *(u16x8*)&xs[row2 * 40 + gg * 8] = st2;
        __syncthreads();
        if (c0 + 32 < Cin) LDST(c0 + 32);   // issue early; consumed next iter

        s16x8 bf[3][2];
#pragma unroll
        for (int j = 0; j < 2; ++j)
#pragma unroll
            for (int k = 0; k < 3; ++k)
                bf[k][j] = *(const s16x8*)&xs[(wt0 + j * 16 + n + k * d) * 40 + g * 8];
#pragma unroll
        for (int i = 0; i < 4; ++i) {
            const unsigned short* wb = &w4[(size_t)(o0 + i * 16 + n) * Cin + c0 + g * 8];
            size_t ps = (size_t)256 * Cin;
            s16x8 a0 = *(const s16x8*)&wb[0];
            s16x8 a1 = *(const s16x8*)&wb[ps];
            s16x8 a2 = *(const s16x8*)&wb[2 * ps];
            s16x8 ar = *(const s16x8*)&wb[3 * ps];
#pragma unroll
            for (int j = 0; j < 2; ++j) {
                accc[i][j] = __builtin_amdgcn_mfma_f32_16x16x32_bf16(a0, bf[0][j], accc[i][j], 0, 0, 0);
                accc[i][j] = __builtin_amdgcn_mfma_f32_16x16x32_bf16(a1, bf[1][j], accc[i][j], 0, 0, 0);
                accc[i][j] = __builtin_amdgcn_mfma_f32_16x16x32_bf16(a2, bf[2][j], accc[i][j], 0, 0, 0);
                accr[i][j] = __builtin_amdgcn_mfma_f32_16x16x32_bf16(ar, bf[2][j], accr[i][j], 0, 0, 0);
            }
        }
    }
#undef LDST

    // epilogue: D row (o-local) = g*4 + reg, col (t-local) = n
#pragma unroll
    for (int i = 0; i < 4; ++i) {
        int ob = o0 + i * 16 + g * 4;
        float cbv0 = cb[ob], cbv1 = cb[ob + 1], cbv2 = cb[ob + 2], cbv3 = cb[ob + 3];
        float rbv0 = rb[ob], rbv1 = rb[ob + 1], rbv2 = rb[ob + 2], rbv3 = rb[ob + 3];
        float ps0 = 0.f, ps1 = 0.f, ps2 = 0.f, ps3 = 0.f;
#pragma unroll
        for (int j = 0; j < 2; ++j) {
            int t = t0 + wt0 + j * 16 + n;
            float v0 = fmaxf(accc[i][j][0] + cbv0, 0.f) + accr[i][j][0] + rbv0;
            float v1 = fmaxf(accc[i][j][1] + cbv1, 0.f) + accr[i][j][1] + rbv1;
            float v2 = fmaxf(accc[i][j][2] + cbv2, 0.f) + accr[i][j][2] + rbv2;
            float v3 = fmaxf(accc[i][j][3] + cbv3, 0.f) + accr[i][j][3] + rbv3;
            ps0 += v0; ps1 += v1; ps2 += v2; ps3 += v3;
            if (!do_pool) {
                u16x4 pk;
                pk[0] = f2bf(v0); pk[1] = f2bf(v1); pk[2] = f2bf(v2); pk[3] = f2bf(v3);
                *(u16x4*)&out[((size_t)b * TP + t) * HID + ob] = pk;
            }
        }
        if (do_pool) {
#pragma unroll
            for (int msk = 1; msk < 16; msk <<= 1) {
                ps0 += __shfl_xor(ps0, msk);
                ps1 += __shfl_xor(ps1, msk);
                ps2 += __shfl_xor(ps2, msk);
                ps3 += __shfl_xor(ps3, msk);
            }
            if (n == 0) {
                pool_s[wid][i * 16 + g * 4 + 0] = ps0;
                pool_s[wid][i * 16 + g * 4 + 1] = ps1;
                pool_s[wid][i * 16 + g * 4 + 2] = ps2;
                pool_s[wid][i * 16 + g * 4 + 3] = ps3;
            }
        }
    }
    if (do_pool) {
        __syncthreads();
        if (tid < 64) {
            float s = pool_s[0][tid] + pool_s[1][tid] + pool_s[2][tid] + pool_s[3][tid];
            pool_out[((size_t)b * 8 + blockIdx.x) * HID + o0 + tid] = s;
        }
    }
}

// ---------------------------------------------------------------------------
// final: fc on pooled sums (8 t-slices) + MMD reduce.
// ---------------------------------------------------------------------------
__global__ __launch_bounds__(256) void final_kernel(
    const float* __restrict__ pp, const float* __restrict__ fcw,
    const float* __restrict__ fcb, const float* __restrict__ partials,
    float* __restrict__ dout)
{
    int tid = threadIdx.x;
    if (tid < 128) {
        int b = tid >> 2, k = tid & 3;
        float s = 0.f;
        for (int c = 0; c < HID; ++c) {
            float pc = 0.f;
#pragma unroll
            for (int xs = 0; xs < 8; ++xs) pc += pp[((size_t)b * 8 + xs) * HID + c];
            s += pc * fcw[k * HID + c];
        }
        dout[tid] = fcb[k] + s * (1.f / 1024.f);
    } else if (tid < 192) {
        int lane = tid - 128;
        float s = 0.f;
        for (int j = 0; j < 8; ++j) s += partials[lane + 64 * j];
        for (int off = 32; off; off >>= 1) s += __shfl_down(s, off);
        if (lane == 0) dout[128] = s * (1.f / (32.f * 32.f * 512.f));
    }
}

// ---------------------------------------------------------------------------
extern "C" void kernel_launch(void* const* d_in, const int* in_sizes, int n_in,
                              void* d_out, int out_size, void* d_ws, size_t ws_size,
                              hipStream_t stream)
{
    const float* feat1 = (const float*)d_in[0];
    const float* feat2 = (const float*)d_in[1];
    const float* wq_a = (const float*)d_in[2];
    const float* bq_a = (const float*)d_in[3];
    const float* wk_a = (const float*)d_in[4];
    const float* bk_a = (const float*)d_in[5];
    const float* wv_a = (const float*)d_in[6];
    const float* bv_a = (const float*)d_in[7];
    const float* wq_b = (const float*)d_in[8];
    const float* bq_b = (const float*)d_in[9];
    const float* wk_b = (const float*)d_in[10];
    const float* bk_b = (const float*)d_in[11];
    const float* wv_b = (const float*)d_in[12];
    const float* bv_b = (const float*)d_in[13];
    const float* cw0 = (const float*)d_in[14];
    const float* cb0 = (const float*)d_in[15];
    const float* rw0 = (const float*)d_in[16];
    const float* rb0 = (const float*)d_in[17];
    const float* cw1 = (const float*)d_in[18];
    const float* cb1 = (const float*)d_in[19];
    const float* rw1 = (const float*)d_in[20];
    const float* rb1 = (const float*)d_in[21];
    const float* cw2 = (const float*)d_in[22];
    const float* cb2 = (const float*)d_in[23];
    const float* rw2 = (const float*)d_in[24];
    const float* rb2 = (const float*)d_in[25];
    const float* fcw = (const float*)d_in[26];
    const float* fcb = (const float*)d_in[27];
    float* dout = (float*)d_out;

    // workspace layout (float offsets):
    //   Qbf @ 0 (1048576), Kbf @ 1048576, Vt @ 2097152
    //   f1tf @ 3145728 (fp32 2097152), f2tf @ 5242880
    //   xbuf @ 7340032 (bf16 [32][1024][128])
    //   wbuf @ 9437184 (tcn bf16 planes, 327680 floats)
    //   xbf1 @ 9798144, xbf2 @ 10846720 (bf16 inputs)
    //   qkvw @ 11895296 (49152 floats)
    //   poolpart @ 11944448 (32*8*256 = 65536 floats)
    //   mmdpart @ 12009984 (512)
    //   h_a aliases 0..4194304 ; h_b aliases 4194304..8388608
    float* ws = (float*)d_ws;
    unsigned short* Qbf = (unsigned short*)ws;
    unsigned short* Kbf = (unsigned short*)(ws + 1048576);
    unsigned short* Vt  = (unsigned short*)(ws + 2097152);
    float* f1tf = ws + 3145728;
    float* f2tf = ws + 5242880;
    unsigned short* xbuf = (unsigned short*)(ws + 7340032);
    unsigned short* wbuf = (unsigned short*)(ws + 9437184);
    unsigned short* wb0 = wbuf;
    unsigned short* wb1 = wbuf + 131072;
    unsigned short* wb2 = wbuf + 393216;
    unsigned short* xbf1 = (unsigned short*)(ws + 9798144);
    unsigned short* xbf2 = (unsigned short*)(ws + 10846720);
    unsigned short* qkvw = (unsigned short*)(ws + 11895296);
    unsigned short* w3a = qkvw;
    unsigned short* w3b = qkvw + 3 * 16384;
    float* poolpart = ws + 11944448;
    float* mmdpart  = ws + 12009984;
    unsigned short* h_a = (unsigned short*)ws;
    unsigned short* h_b = (unsigned short*)(ws + 4194304);

    // prep: transpose-convert features; convert weights
    t2bf_kernel<<<dim3(16, 4, 32), 256, 0, stream>>>(feat1, xbf1);
    t2bf_kernel<<<dim3(16, 4, 32), 256, 0, stream>>>(feat2, xbf2);
    prep_qkvw_kernel<<<dim3(384), 256, 0, stream>>>(wq_a, wk_a, wv_a, wq_b, wk_b, wv_b, qkvw);
    prep_w_kernel<<<dim3(512), 256, 0, stream>>>(cw0, rw0, wb0, 128);
    prep_w_kernel<<<dim3(1024), 256, 0, stream>>>(cw1, rw1, wb1, 256);
    prep_w_kernel<<<dim3(1024), 256, 0, stream>>>(cw2, rw2, wb2, 256);

    // branch A: Q from feat2 (xbf2), K/V from feat1 (xbf1)
    proj_mfma_kernel<<<dim3(16, 32), 256, 0, stream>>>(
        xbf2, (long long)TT * FF, xbf1, (long long)TT * FF, w3a,
        bq_a, bk_a, bv_a, Qbf, Kbf, Vt);
    attn_mfma_kernel<<<dim3(8, 32), 256, 0, stream>>>(
        Qbf, Kbf, Vt, feat1, 65536LL, 512, 1, f1tf, xbuf, 0);

    // branch B: Q from updated f1 (xbuf rows 0..511), K/V from feat2 (xbf2)
    proj_mfma_kernel<<<dim3(16, 32), 256, 0, stream>>>(
        xbuf, (long long)TP * FF, xbf2, (long long)TT * FF, w3b,
        bq_b, bk_b, bv_b, Qbf, Kbf, Vt);
    attn_mfma_kernel<<<dim3(8, 32), 256, 0, stream>>>(
        Qbf, Kbf, Vt, feat2, 65536LL, 512, 1, f2tf, xbuf, 512);

    // MMD partials (before TCN overwrites f1tf/f2tf regions)
    mmd_kernel<<<dim3(512), 256, 0, stream>>>(f1tf, f2tf, mmdpart);

    // TCN stack: xbuf(128ch) -> h_a -> h_b -> pooled (fused)
    tcn_mfma_kernel<<<dim3(8, 4, 32), 256, 0, stream>>>(xbuf, 128, 1, wb0, cb0, rb0, h_a, nullptr, 0);
    tcn_mfma_kernel<<<dim3(8, 4, 32), 256, 0, stream>>>(h_a, 256, 2, wb1, cb1, rb1, h_b, nullptr, 0);
    tcn_mfma_kernel<<<dim3(8, 4, 32), 256, 0, stream>>>(h_b, 256, 4, wb2, cb2, rb2, h_a, poolpart, 1);

    final_kernel<<<dim3(1), 256, 0, stream>>>(poolpart, fcw, fcb, mmdpart, dout);
}

// Round 6
// 244.918 us; speedup vs baseline: 1.3678x; 1.3678x over previous
//
#include <hip/hip_runtime.h>

#define BB 32
#define TT 512
#define FF 128
#define HID 256
#define TP 1024

typedef __attribute__((ext_vector_type(8))) short s16x8;
typedef __attribute__((ext_vector_type(8))) unsigned short u16x8;
typedef __attribute__((ext_vector_type(4))) unsigned short u16x4;
typedef __attribute__((ext_vector_type(4))) float f32x4;

static __device__ __forceinline__ unsigned short f2bf(float f) {
    unsigned u = __builtin_bit_cast(unsigned, f);
    u = (u + 0x7FFFu + ((u >> 16) & 1u)) >> 16;
    return (unsigned short)u;
}
static __device__ __forceinline__ float bf2f(unsigned short b) {
    return __builtin_bit_cast(float, ((unsigned)b) << 16);
}

// ---------------------------------------------------------------------------
// transpose-convert: src fp32 [b][128][512] -> dst bf16 [b][512][128].
// ---------------------------------------------------------------------------
__global__ __launch_bounds__(256) void t2bf_kernel(
    const float* __restrict__ src, unsigned short* __restrict__ dst)
{
    int t0 = blockIdx.x * 32, c0 = blockIdx.y * 32, b = blockIdx.z;
    __shared__ float tile[32][33];
    int tid = threadIdx.x;
    for (int l = tid; l < 1024; l += 256) {
        int c = l >> 5, t = l & 31;
        tile[c][t] = src[((size_t)b * FF + c0 + c) * TT + t0 + t];
    }
    __syncthreads();
    for (int l = tid; l < 1024; l += 256) {
        int t = l >> 5, c = l & 31;
        dst[((size_t)b * TT + t0 + t) * FF + c0 + c] = f2bf(tile[c][t]);
    }
}

// ---------------------------------------------------------------------------
// QKV weight prep: out bf16 [6][128][128]; planes 0,3 (wq_a, wq_b) pre-scaled.
// ---------------------------------------------------------------------------
__global__ __launch_bounds__(256) void prep_qkvw_kernel(
    const float* __restrict__ wqa, const float* __restrict__ wka,
    const float* __restrict__ wva, const float* __restrict__ wqb,
    const float* __restrict__ wkb, const float* __restrict__ wvb,
    unsigned short* __restrict__ out)
{
    int idx = blockIdx.x * 256 + threadIdx.x;
    if (idx >= 6 * 16384) return;
    int p = idx >> 14, rc = idx & 16383;
    const float* srcs[6] = {wqa, wka, wva, wqb, wkb, wvb};
    float v = srcs[p][rc];
    if (p == 0 || p == 3) v *= 0.088388347648318447f;
    out[idx] = f2bf(v);
}

// ---------------------------------------------------------------------------
// QKV projection via MFMA.  grid (16, 32), block 256 = 4 waves.
// ---------------------------------------------------------------------------
__global__ __launch_bounds__(256) void proj_mfma_kernel(
    const unsigned short* __restrict__ xq_src, long long xq_bs,
    const unsigned short* __restrict__ xkv_src, long long xkv_bs,
    const unsigned short* __restrict__ w3,
    const float* __restrict__ bq, const float* __restrict__ bk,
    const float* __restrict__ bv,
    unsigned short* __restrict__ Qo, unsigned short* __restrict__ Ko,
    unsigned short* __restrict__ Vt)
{
    int t0 = blockIdx.x * 32, b = blockIdx.y;
    __shared__ __align__(16) unsigned short xsq[32 * 136];
    __shared__ __align__(16) unsigned short xskv[32 * 136];
    int tid = threadIdx.x;
    int wid = tid >> 6, lane = tid & 63;
    int n = lane & 15, g = lane >> 4;
    int tsub = (wid & 1) * 16, fh = (wid >> 1) * 64;

    for (int l = tid; l < 512; l += 256) {
        int r = l >> 4, cc = l & 15;
        *(u16x8*)&xsq[r * 136 + cc * 8] =
            *(const u16x8*)&xq_src[xq_bs * b + (size_t)(t0 + r) * FF + cc * 8];
        *(u16x8*)&xskv[r * 136 + cc * 8] =
            *(const u16x8*)&xkv_src[xkv_bs * b + (size_t)(t0 + r) * FF + cc * 8];
    }
    __syncthreads();

    f32x4 acc[3][4];
#pragma unroll
    for (int p = 0; p < 3; ++p)
#pragma unroll
        for (int i = 0; i < 4; ++i) acc[p][i] = (f32x4){0.f, 0.f, 0.f, 0.f};

#pragma unroll
    for (int kk = 0; kk < 4; ++kk) {
        s16x8 bxq = *(const s16x8*)&xsq[(tsub + n) * 136 + kk * 32 + g * 8];
        s16x8 bxkv = *(const s16x8*)&xskv[(tsub + n) * 136 + kk * 32 + g * 8];
#pragma unroll
        for (int i = 0; i < 4; ++i) {
            const unsigned short* wb = &w3[(size_t)(fh + i * 16 + n) * 128 + kk * 32 + g * 8];
            s16x8 a0 = *(const s16x8*)&wb[0];
            s16x8 a1 = *(const s16x8*)&wb[16384];
            s16x8 a2 = *(const s16x8*)&wb[32768];
            acc[0][i] = __builtin_amdgcn_mfma_f32_16x16x32_bf16(a0, bxq, acc[0][i], 0, 0, 0);
            acc[1][i] = __builtin_amdgcn_mfma_f32_16x16x32_bf16(a1, bxkv, acc[1][i], 0, 0, 0);
            acc[2][i] = __builtin_amdgcn_mfma_f32_16x16x32_bf16(a2, bxkv, acc[2][i], 0, 0, 0);
        }
    }

    const float scale = 0.088388347648318447f;
    int t = t0 + tsub + n;
#pragma unroll
    for (int i = 0; i < 4; ++i) {
        int fb = fh + i * 16 + g * 4;
        u16x4 pk;
#pragma unroll
        for (int r = 0; r < 4; ++r) pk[r] = f2bf(acc[0][i][r] + bq[fb + r] * scale);
        *(u16x4*)&Qo[((size_t)b * TT + t) * FF + fb] = pk;
#pragma unroll
        for (int r = 0; r < 4; ++r) pk[r] = f2bf(acc[1][i][r] + bk[fb + r]);
        *(u16x4*)&Ko[((size_t)b * TT + t) * FF + fb] = pk;
#pragma unroll
        for (int r = 0; r < 4; ++r)
            Vt[((size_t)b * FF + fb + r) * TT + t] = f2bf(acc[2][i][r] + bv[fb + r]);
    }
}

// ---------------------------------------------------------------------------
// Flash attention via MFMA.  grid (8, 32), block 256 = 4 waves.
// ---------------------------------------------------------------------------
__global__ __launch_bounds__(256) void attn_mfma_kernel(
    const unsigned short* __restrict__ Qb, const unsigned short* __restrict__ Kb,
    const unsigned short* __restrict__ Vtb,
    const float* __restrict__ orig, long long bso, int cso, int tso,
    float* __restrict__ out_tf, unsigned short* __restrict__ out_x, int xoff)
{
    __shared__ __align__(16) unsigned short Ks[64 * 136];
    __shared__ __align__(16) unsigned short Vs[128 * 72];
    __shared__ __align__(16) unsigned short Ps[4 * 16 * 68];

    int t0 = blockIdx.x * 64, b = blockIdx.y;
    int tid = threadIdx.x;
    int wid = tid >> 6, lane = tid & 63;
    int n = lane & 15, g = lane >> 4;
    int q0 = t0 + wid * 16;
    unsigned short* Pw = &Ps[wid * 1088];

    s16x8 qf[4];
#pragma unroll
    for (int kk = 0; kk < 4; ++kk)
        qf[kk] = *(const s16x8*)&Qb[((size_t)b * TT + q0 + n) * FF + kk * 32 + g * 8];

    u16x8 kst[4], vst[4];
#pragma unroll
    for (int ii = 0; ii < 4; ++ii) {
        int l = tid + 256 * ii;
        kst[ii] = *(const u16x8*)&Kb[((size_t)b * TT + (l >> 4)) * FF + (l & 15) * 8];
        vst[ii] = *(const u16x8*)&Vtb[((size_t)b * FF + (l >> 3)) * TT + (l & 7) * 8];
    }

    f32x4 O[8];
#pragma unroll
    for (int ft = 0; ft < 8; ++ft) O[ft] = (f32x4){0.f, 0.f, 0.f, 0.f};
    float m[4] = {-1e30f, -1e30f, -1e30f, -1e30f};
    float lsum[4] = {0.f, 0.f, 0.f, 0.f};

    for (int it = 0; it < 8; ++it) {
        __syncthreads();
#pragma unroll
        for (int ii = 0; ii < 4; ++ii) {
            int l = tid + 256 * ii;
            *(u16x8*)&Ks[(l >> 4) * 136 + (l & 15) * 8] = kst[ii];
            *(u16x8*)&Vs[(l >> 3) * 72 + (l & 7) * 8] = vst[ii];
        }
        __syncthreads();
        if (it < 7) {
            int s0n = (it + 1) * 64;
#pragma unroll
            for (int ii = 0; ii < 4; ++ii) {
                int l = tid + 256 * ii;
                kst[ii] = *(const u16x8*)&Kb[((size_t)b * TT + s0n + (l >> 4)) * FF + (l & 15) * 8];
                vst[ii] = *(const u16x8*)&Vtb[((size_t)b * FF + (l >> 3)) * TT + s0n + (l & 7) * 8];
            }
        }

        f32x4 acc[4];
#pragma unroll
        for (int st = 0; st < 4; ++st) acc[st] = (f32x4){0.f, 0.f, 0.f, 0.f};
#pragma unroll
        for (int kk = 0; kk < 4; ++kk) {
#pragma unroll
            for (int st = 0; st < 4; ++st) {
                s16x8 kf = *(const s16x8*)&Ks[(st * 16 + n) * 136 + kk * 32 + g * 8];
                acc[st] = __builtin_amdgcn_mfma_f32_16x16x32_bf16(qf[kk], kf, acc[st], 0, 0, 0);
            }
        }

        float mnew[4], c[4], rs[4];
#pragma unroll
        for (int r = 0; r < 4; ++r) {
            float tm = fmaxf(fmaxf(acc[0][r], acc[1][r]), fmaxf(acc[2][r], acc[3][r]));
#pragma unroll
            for (int msk = 1; msk < 16; msk <<= 1) tm = fmaxf(tm, __shfl_xor(tm, msk));
            mnew[r] = fmaxf(m[r], tm);
            c[r] = __expf(m[r] - mnew[r]);
            m[r] = mnew[r];
            rs[r] = 0.f;
        }
#pragma unroll
        for (int st = 0; st < 4; ++st) {
#pragma unroll
            for (int r = 0; r < 4; ++r) {
                float p = __expf(acc[st][r] - mnew[r]);
                rs[r] += p;
                Pw[(g * 4 + r) * 68 + st * 16 + n] = f2bf(p);
            }
        }
#pragma unroll
        for (int r = 0; r < 4; ++r) {
#pragma unroll
            for (int msk = 1; msk < 16; msk <<= 1) rs[r] += __shfl_xor(rs[r], msk);
            lsum[r] = lsum[r] * c[r] + rs[r];
        }
#pragma unroll
        for (int ft = 0; ft < 8; ++ft) {
#pragma unroll
            for (int r = 0; r < 4; ++r) O[ft][r] *= c[r];
        }

#pragma unroll
        for (int ks = 0; ks < 2; ++ks) {
            s16x8 pf = *(const s16x8*)&Pw[n * 68 + ks * 32 + g * 8];
#pragma unroll
            for (int ft = 0; ft < 8; ++ft) {
                s16x8 vf = *(const s16x8*)&Vs[(ft * 16 + n) * 72 + ks * 32 + g * 8];
                O[ft] = __builtin_amdgcn_mfma_f32_16x16x32_bf16(pf, vf, O[ft], 0, 0, 0);
            }
        }
    }

    float rinv[4];
#pragma unroll
    for (int r = 0; r < 4; ++r) rinv[r] = 1.f / lsum[r];
#pragma unroll
    for (int ft = 0; ft < 8; ++ft) {
        int f = ft * 16 + n;
#pragma unroll
        for (int r = 0; r < 4; ++r) {
            int q = q0 + g * 4 + r;
            float val = O[ft][r] * rinv[r];
            float xv = orig[bso * b + (size_t)f * cso + (size_t)q * tso];
            float res = val * xv + xv;
            out_tf[((size_t)b * TT + q) * FF + f] = res;
            out_x[((size_t)b * TP + xoff + q) * FF + f] = f2bf(res);
        }
    }
}

// ---------------------------------------------------------------------------
// MMD partials per timepoint (fp32 exact).
// ---------------------------------------------------------------------------
__global__ __launch_bounds__(256) void mmd_kernel(
    const float* __restrict__ f1, const float* __restrict__ f2,
    float* __restrict__ partials)
{
    int t = blockIdx.x;
    __shared__ float v1[32][129], v2[32][129];
    __shared__ float red[256];
    int tid = threadIdx.x;
    for (int l = tid; l < 4096; l += 256) {
        int i = l >> 7, f = l & 127;
        v1[i][f] = f1[((size_t)i * TT + t) * FF + f];
        v2[i][f] = f2[((size_t)i * TT + t) * FF + f];
    }
    __syncthreads();
    float s = 0.f;
    for (int r = 0; r < 4; ++r) {
        int p = tid + 256 * r;
        int i = p >> 5, j = p & 31;
        float dxx = 0.f, dyy = 0.f, dxy = 0.f;
        for (int f = 0; f < 128; ++f) {
            float a = v1[i][f], b_ = v1[j][f], c = v2[i][f], d = v2[j][f];
            float e1 = a - b_, e2 = c - d, e3 = a - d;
            dxx += e1 * e1; dyy += e2 * e2; dxy += e3 * e3;
        }
        s += __expf(-0.5f * dxx) + __expf(-0.5f * dyy) - 2.f * __expf(-0.5f * dxy);
    }
    red[tid] = s;
    __syncthreads();
    for (int off = 128; off; off >>= 1) {
        if (tid < off) red[tid] += red[tid + off];
        __syncthreads();
    }
    if (tid == 0) partials[t] = red[0];
}

// ---------------------------------------------------------------------------
// TCN weight prep: w4[plane][o][c] bf16, planes 0..2 = conv taps, 3 = residual.
// ---------------------------------------------------------------------------
__global__ __launch_bounds__(256) void prep_w_kernel(
    const float* __restrict__ cw, const float* __restrict__ rw,
    unsigned short* __restrict__ out, int Cin)
{
    int idx = blockIdx.x * 256 + threadIdx.x;
    int total = 4 * 256 * Cin;
    if (idx >= total) return;
    int p = idx / (256 * Cin);
    int rem = idx - p * 256 * Cin;
    int o = rem / Cin, c = rem - o * Cin;
    float v = (p < 3) ? cw[(o * Cin + c) * 3 + p] : rw[o * Cin + c];
    out[idx] = f2bf(v);
}

// ---------------------------------------------------------------------------
// TCN layer via MFMA, weights staged in LDS.
// x bf16 [b][t][Cin]; w4 bf16 [4][256][Cin]; out bf16 [b][t][256].
// grid (8 t-tiles of 128, 4 o-tiles, 32 b), block 256 = 4 waves (2o x 2t);
// wave tile 32o x 64t.  Both x and w tiles staged load-early/write-late.
// ---------------------------------------------------------------------------
__global__ __launch_bounds__(256, 3) void tcn_mfma_kernel(
    const unsigned short* __restrict__ x, int Cin, int d,
    const unsigned short* __restrict__ w4,
    const float* __restrict__ cb, const float* __restrict__ rb,
    unsigned short* __restrict__ out, float* __restrict__ pool_out, int do_pool)
{
    int t0 = blockIdx.x * 128, o0 = blockIdx.y * 64, b = blockIdx.z;
    __shared__ __align__(16) unsigned short xs[136 * 40];   // [row][c] pitch 40
    __shared__ __align__(16) unsigned short wsh[4 * 64 * 40]; // [plane][o][c]
    __shared__ float pool_s[2][64];
    int tid = threadIdx.x;
    int wid = tid >> 6, lane = tid & 63;
    int n = lane & 15, g = lane >> 4;
    int wo = (wid & 1) * 32;        // o offset of this wave
    int wt = (wid >> 1) * 64;       // t offset of this wave
    int d2 = 2 * d;
    int nrow = 128 + d2;            // <= 136
    const unsigned short* xb = x + (size_t)b * TP * Cin;

    // staging geometry
    int gg = tid & 3;
    int xrow0 = tid >> 2;           // 0..63
    int xrow1 = xrow0 + 64;         // 64..127
    int xrow2 = xrow0 + 128;        // 128..191, valid iff < nrow
    bool xv2 = xrow2 < nrow;
    int tg0 = t0 - d2 + xrow0;      // only this can be < 0; rows 64+ always in range
    int worow = tid >> 2;           // w o-row 0..63
    const unsigned short* wbase = w4 + (size_t)(o0 + worow) * Cin + gg * 8;
    size_t wps = (size_t)256 * Cin; // plane stride

    u16x8 sx0, sx1, sx2, sw0, sw1, sw2, sw3;
    const u16x8 zz = {0, 0, 0, 0, 0, 0, 0, 0};
#define LDST(C0)                                                               \
    do {                                                                       \
        sx0 = (tg0 >= 0) ? *(const u16x8*)&xb[(size_t)tg0 * Cin + (C0) + gg * 8] : zz; \
        sx1 = *(const u16x8*)&xb[(size_t)(tg0 + 64) * Cin + (C0) + gg * 8];    \
        sx2 = xv2 ? *(const u16x8*)&xb[(size_t)(tg0 + 128) * Cin + (C0) + gg * 8] : zz; \
        sw0 = *(const u16x8*)&wbase[(C0)];                                     \
        sw1 = *(const u16x8*)&wbase[wps + (C0)];                               \
        sw2 = *(const u16x8*)&wbase[2 * wps + (C0)];                           \
        sw3 = *(const u16x8*)&wbase[3 * wps + (C0)];                           \
    } while (0)

    f32x4 accc[2][4], accr[2][4];
#pragma unroll
    for (int i = 0; i < 2; ++i)
#pragma unroll
        for (int j = 0; j < 4; ++j) {
            accc[i][j] = (f32x4){0.f, 0.f, 0.f, 0.f};
            accr[i][j] = (f32x4){0.f, 0.f, 0.f, 0.f};
        }

    LDST(0);
    for (int c0 = 0; c0 < Cin; c0 += 32) {
        __syncthreads();   // previous slice's LDS reads complete
        *(u16x8*)&xs[xrow0 * 40 + gg * 8] = sx0;
        *(u16x8*)&xs[xrow1 * 40 + gg * 8] = sx1;
        if (xv2) *(u16x8*)&xs[xrow2 * 40 + gg * 8] = sx2;
        *(u16x8*)&wsh[worow * 40 + gg * 8] = sw0;
        *(u16x8*)&wsh[2560 + worow * 40 + gg * 8] = sw1;
        *(u16x8*)&wsh[5120 + worow * 40 + gg * 8] = sw2;
        *(u16x8*)&wsh[7680 + worow * 40 + gg * 8] = sw3;
        __syncthreads();
        if (c0 + 32 < Cin) LDST(c0 + 32);   // prefetch next slice into regs

#pragma unroll
        for (int i = 0; i < 2; ++i) {
            int wrow = (wo + i * 16 + n) * 40 + g * 8;
            s16x8 a0 = *(const s16x8*)&wsh[wrow];
            s16x8 a1 = *(const s16x8*)&wsh[2560 + wrow];
            s16x8 a2 = *(const s16x8*)&wsh[5120 + wrow];
            s16x8 ar = *(const s16x8*)&wsh[7680 + wrow];
#pragma unroll
            for (int j = 0; j < 4; ++j) {
                int tl = wt + j * 16 + n;
                s16x8 b0 = *(const s16x8*)&xs[tl * 40 + g * 8];
                s16x8 b1 = *(const s16x8*)&xs[(tl + d) * 40 + g * 8];
                s16x8 b2 = *(const s16x8*)&xs[(tl + d2) * 40 + g * 8];
                accc[i][j] = __builtin_amdgcn_mfma_f32_16x16x32_bf16(a0, b0, accc[i][j], 0, 0, 0);
                accc[i][j] = __builtin_amdgcn_mfma_f32_16x16x32_bf16(a1, b1, accc[i][j], 0, 0, 0);
                accc[i][j] = __builtin_amdgcn_mfma_f32_16x16x32_bf16(a2, b2, accc[i][j], 0, 0, 0);
                accr[i][j] = __builtin_amdgcn_mfma_f32_16x16x32_bf16(ar, b2, accr[i][j], 0, 0, 0);
            }
        }
    }
#undef LDST

    // epilogue: D row (o-local) = g*4 + reg, col (t-local) = n
#pragma unroll
    for (int i = 0; i < 2; ++i) {
        int ob = o0 + wo + i * 16 + g * 4;
        float cbv0 = cb[ob], cbv1 = cb[ob + 1], cbv2 = cb[ob + 2], cbv3 = cb[ob + 3];
        float rbv0 = rb[ob], rbv1 = rb[ob + 1], rbv2 = rb[ob + 2], rbv3 = rb[ob + 3];
        float ps0 = 0.f, ps1 = 0.f, ps2 = 0.f, ps3 = 0.f;
#pragma unroll
        for (int j = 0; j < 4; ++j) {
            int t = t0 + wt + j * 16 + n;
            float v0 = fmaxf(accc[i][j][0] + cbv0, 0.f) + accr[i][j][0] + rbv0;
            float v1 = fmaxf(accc[i][j][1] + cbv1, 0.f) + accr[i][j][1] + rbv1;
            float v2 = fmaxf(accc[i][j][2] + cbv2, 0.f) + accr[i][j][2] + rbv2;
            float v3 = fmaxf(accc[i][j][3] + cbv3, 0.f) + accr[i][j][3] + rbv3;
            ps0 += v0; ps1 += v1; ps2 += v2; ps3 += v3;
            if (!do_pool) {
                u16x4 pk;
                pk[0] = f2bf(v0); pk[1] = f2bf(v1); pk[2] = f2bf(v2); pk[3] = f2bf(v3);
                *(u16x4*)&out[((size_t)b * TP + t) * HID + ob] = pk;
            }
        }
        if (do_pool) {
#pragma unroll
            for (int msk = 1; msk < 16; msk <<= 1) {
                ps0 += __shfl_xor(ps0, msk);
                ps1 += __shfl_xor(ps1, msk);
                ps2 += __shfl_xor(ps2, msk);
                ps3 += __shfl_xor(ps3, msk);
            }
            if (n == 0) {
                int ol = wo + i * 16 + g * 4;
                pool_s[wid >> 1][ol + 0] = ps0;
                pool_s[wid >> 1][ol + 1] = ps1;
                pool_s[wid >> 1][ol + 2] = ps2;
                pool_s[wid >> 1][ol + 3] = ps3;
            }
        }
    }
    if (do_pool) {
        __syncthreads();
        if (tid < 64) {
            float s = pool_s[0][tid] + pool_s[1][tid];
            pool_out[((size_t)b * 8 + blockIdx.x) * HID + o0 + tid] = s;
        }
    }
}

// ---------------------------------------------------------------------------
// final: fc on pooled sums (8 t-slices) + MMD reduce.
// ---------------------------------------------------------------------------
__global__ __launch_bounds__(256) void final_kernel(
    const float* __restrict__ pp, const float* __restrict__ fcw,
    const float* __restrict__ fcb, const float* __restrict__ partials,
    float* __restrict__ dout)
{
    int tid = threadIdx.x;
    if (tid < 128) {
        int b = tid >> 2, k = tid & 3;
        float s = 0.f;
        for (int c = 0; c < HID; ++c) {
            float pc = 0.f;
#pragma unroll
            for (int xs = 0; xs < 8; ++xs) pc += pp[((size_t)b * 8 + xs) * HID + c];
            s += pc * fcw[k * HID + c];
        }
        dout[tid] = fcb[k] + s * (1.f / 1024.f);
    } else if (tid < 192) {
        int lane = tid - 128;
        float s = 0.f;
        for (int j = 0; j < 8; ++j) s += partials[lane + 64 * j];
        for (int off = 32; off; off >>= 1) s += __shfl_down(s, off);
        if (lane == 0) dout[128] = s * (1.f / (32.f * 32.f * 512.f));
    }
}

// ---------------------------------------------------------------------------
extern "C" void kernel_launch(void* const* d_in, const int* in_sizes, int n_in,
                              void* d_out, int out_size, void* d_ws, size_t ws_size,
                              hipStream_t stream)
{
    const float* feat1 = (const float*)d_in[0];
    const float* feat2 = (const float*)d_in[1];
    const float* wq_a = (const float*)d_in[2];
    const float* bq_a = (const float*)d_in[3];
    const float* wk_a = (const float*)d_in[4];
    const float* bk_a = (const float*)d_in[5];
    const float* wv_a = (const float*)d_in[6];
    const float* bv_a = (const float*)d_in[7];
    const float* wq_b = (const float*)d_in[8];
    const float* bq_b = (const float*)d_in[9];
    const float* wk_b = (const float*)d_in[10];
    const float* bk_b = (const float*)d_in[11];
    const float* wv_b = (const float*)d_in[12];
    const float* bv_b = (const float*)d_in[13];
    const float* cw0 = (const float*)d_in[14];
    const float* cb0 = (const float*)d_in[15];
    const float* rw0 = (const float*)d_in[16];
    const float* rb0 = (const float*)d_in[17];
    const float* cw1 = (const float*)d_in[18];
    const float* cb1 = (const float*)d_in[19];
    const float* rw1 = (const float*)d_in[20];
    const float* rb1 = (const float*)d_in[21];
    const float* cw2 = (const float*)d_in[22];
    const float* cb2 = (const float*)d_in[23];
    const float* rw2 = (const float*)d_in[24];
    const float* rb2 = (const float*)d_in[25];
    const float* fcw = (const float*)d_in[26];
    const float* fcb = (const float*)d_in[27];
    float* dout = (float*)d_out;

    // workspace layout (float offsets):
    //   Qbf @ 0 (1048576), Kbf @ 1048576, Vt @ 2097152
    //   f1tf @ 3145728 (fp32 2097152), f2tf @ 5242880
    //   xbuf @ 7340032 (bf16 [32][1024][128])
    //   wbuf @ 9437184 (tcn bf16 planes, 327680 floats)
    //   xbf1 @ 9798144, xbf2 @ 10846720 (bf16 inputs)
    //   qkvw @ 11895296 (49152 floats)
    //   poolpart @ 11944448 (32*8*256 = 65536 floats)
    //   mmdpart @ 12009984 (512)
    //   h_a aliases 0..4194304 ; h_b aliases 4194304..8388608
    float* ws = (float*)d_ws;
    unsigned short* Qbf = (unsigned short*)ws;
    unsigned short* Kbf = (unsigned short*)(ws + 1048576);
    unsigned short* Vt  = (unsigned short*)(ws + 2097152);
    float* f1tf = ws + 3145728;
    float* f2tf = ws + 5242880;
    unsigned short* xbuf = (unsigned short*)(ws + 7340032);
    unsigned short* wbuf = (unsigned short*)(ws + 9437184);
    unsigned short* wb0 = wbuf;
    unsigned short* wb1 = wbuf + 131072;
    unsigned short* wb2 = wbuf + 393216;
    unsigned short* xbf1 = (unsigned short*)(ws + 9798144);
    unsigned short* xbf2 = (unsigned short*)(ws + 10846720);
    unsigned short* qkvw = (unsigned short*)(ws + 11895296);
    unsigned short* w3a = qkvw;
    unsigned short* w3b = qkvw + 3 * 16384;
    float* poolpart = ws + 11944448;
    float* mmdpart  = ws + 12009984;
    unsigned short* h_a = (unsigned short*)ws;
    unsigned short* h_b = (unsigned short*)(ws + 4194304);

    // prep: transpose-convert features; convert weights
    t2bf_kernel<<<dim3(16, 4, 32), 256, 0, stream>>>(feat1, xbf1);
    t2bf_kernel<<<dim3(16, 4, 32), 256, 0, stream>>>(feat2, xbf2);
    prep_qkvw_kernel<<<dim3(384), 256, 0, stream>>>(wq_a, wk_a, wv_a, wq_b, wk_b, wv_b, qkvw);
    prep_w_kernel<<<dim3(512), 256, 0, stream>>>(cw0, rw0, wb0, 128);
    prep_w_kernel<<<dim3(1024), 256, 0, stream>>>(cw1, rw1, wb1, 256);
    prep_w_kernel<<<dim3(1024), 256, 0, stream>>>(cw2, rw2, wb2, 256);

    // branch A: Q from feat2 (xbf2), K/V from feat1 (xbf1)
    proj_mfma_kernel<<<dim3(16, 32), 256, 0, stream>>>(
        xbf2, (long long)TT * FF, xbf1, (long long)TT * FF, w3a,
        bq_a, bk_a, bv_a, Qbf, Kbf, Vt);
    attn_mfma_kernel<<<dim3(8, 32), 256, 0, stream>>>(
        Qbf, Kbf, Vt, feat1, 65536LL, 512, 1, f1tf, xbuf, 0);

    // branch B: Q from updated f1 (xbuf rows 0..511), K/V from feat2 (xbf2)
    proj_mfma_kernel<<<dim3(16, 32), 256, 0, stream>>>(
        xbuf, (long long)TP * FF, xbf2, (long long)TT * FF, w3b,
        bq_b, bk_b, bv_b, Qbf, Kbf, Vt);
    attn_mfma_kernel<<<dim3(8, 32), 256, 0, stream>>>(
        Qbf, Kbf, Vt, feat2, 65536LL, 512, 1, f2tf, xbuf, 512);

    // MMD partials (before TCN overwrites f1tf/f2tf regions)
    mmd_kernel<<<dim3(512), 256, 0, stream>>>(f1tf, f2tf, mmdpart);

    // TCN stack: xbuf(128ch) -> h_a -> h_b -> pooled (fused)
    tcn_mfma_kernel<<<dim3(8, 4, 32), 256, 0, stream>>>(xbuf, 128, 1, wb0, cb0, rb0, h_a, nullptr, 0);
    tcn_mfma_kernel<<<dim3(8, 4, 32), 256, 0, stream>>>(h_a, 256, 2, wb1, cb1, rb1, h_b, nullptr, 0);
    tcn_mfma_kernel<<<dim3(8, 4, 32), 256, 0, stream>>>(h_b, 256, 4, wb2, cb2, rb2, h_a, poolpart, 1);

    final_kernel<<<dim3(1), 256, 0, stream>>>(poolpart, fcw, fcb, mmdpart, dout);
}

// Round 7
// 198.535 us; speedup vs baseline: 1.6873x; 1.2336x over previous
//
#include <hip/hip_runtime.h>

#define BB 32
#define TT 512
#define FF 128
#define HID 256
#define TP 1024

typedef __attribute__((ext_vector_type(8))) short s16x8;
typedef __attribute__((ext_vector_type(8))) unsigned short u16x8;
typedef __attribute__((ext_vector_type(4))) unsigned short u16x4;
typedef __attribute__((ext_vector_type(4))) float f32x4;

static __device__ __forceinline__ unsigned short f2bf(float f) {
    unsigned u = __builtin_bit_cast(unsigned, f);
    u = (u + 0x7FFFu + ((u >> 16) & 1u)) >> 16;
    return (unsigned short)u;
}
static __device__ __forceinline__ float bf2f(unsigned short b) {
    return __builtin_bit_cast(float, ((unsigned)b) << 16);
}

// ---------------------------------------------------------------------------
// transpose-convert both features: fp32 [b][128][512] -> bf16 [b][512][128].
// grid (16, 4, 64): z<32 -> feat1->dst1, z>=32 -> feat2->dst2.
// ---------------------------------------------------------------------------
__global__ __launch_bounds__(256) void t2bf_kernel(
    const float* __restrict__ src1, const float* __restrict__ src2,
    unsigned short* __restrict__ dst1, unsigned short* __restrict__ dst2)
{
    int t0 = blockIdx.x * 32, c0 = blockIdx.y * 32;
    int sel = blockIdx.z >> 5, b = blockIdx.z & 31;
    const float* src = sel ? src2 : src1;
    unsigned short* dst = sel ? dst2 : dst1;
    __shared__ float tile[32][33];
    int tid = threadIdx.x;
    for (int l = tid; l < 1024; l += 256) {
        int c = l >> 5, t = l & 31;
        tile[c][t] = src[((size_t)b * FF + c0 + c) * TT + t0 + t];
    }
    __syncthreads();
    for (int l = tid; l < 1024; l += 256) {
        int t = l >> 5, c = l & 31;
        dst[((size_t)b * TT + t0 + t) * FF + c0 + c] = f2bf(tile[c][t]);
    }
}

// ---------------------------------------------------------------------------
// All weight prep in one launch.
//   [0, 98304):        qkvw bf16 [6][128][128], planes 0,3 pre-scaled
//   [98304, 229376):   tcn w0 (Cin=128)
//   [229376, 491520):  tcn w1 (Cin=256)
//   [491520, 753664):  tcn w2 (Cin=256)
// grid (2944), block 256.
// ---------------------------------------------------------------------------
static __device__ __forceinline__ void tcnw_prep(
    int idx, const float* __restrict__ cw, const float* __restrict__ rw,
    unsigned short* __restrict__ out, int Cin)
{
    int p = idx / (256 * Cin);
    int rem = idx - p * 256 * Cin;
    int o = rem / Cin, c = rem - o * Cin;
    float v = (p < 3) ? cw[(o * Cin + c) * 3 + p] : rw[o * Cin + c];
    out[idx] = f2bf(v);
}

__global__ __launch_bounds__(256) void prep_all_kernel(
    const float* __restrict__ wqa, const float* __restrict__ wka,
    const float* __restrict__ wva, const float* __restrict__ wqb,
    const float* __restrict__ wkb, const float* __restrict__ wvb,
    const float* __restrict__ cw0, const float* __restrict__ rw0,
    const float* __restrict__ cw1, const float* __restrict__ rw1,
    const float* __restrict__ cw2, const float* __restrict__ rw2,
    unsigned short* __restrict__ qkvw, unsigned short* __restrict__ wb0,
    unsigned short* __restrict__ wb1, unsigned short* __restrict__ wb2)
{
    int idx = blockIdx.x * 256 + threadIdx.x;
    if (idx < 98304) {
        int p = idx >> 14, rc = idx & 16383;
        const float* srcs[6] = {wqa, wka, wva, wqb, wkb, wvb};
        float v = srcs[p][rc];
        if (p == 0 || p == 3) v *= 0.088388347648318447f;
        qkvw[idx] = f2bf(v);
    } else if (idx < 229376) {
        tcnw_prep(idx - 98304, cw0, rw0, wb0, 128);
    } else if (idx < 491520) {
        tcnw_prep(idx - 229376, cw1, rw1, wb1, 256);
    } else if (idx < 753664) {
        tcnw_prep(idx - 491520, cw2, rw2, wb2, 256);
    }
}

// ---------------------------------------------------------------------------
// QKV projection via MFMA.  grid (16, 32), block 256 = 4 waves.
// ---------------------------------------------------------------------------
__global__ __launch_bounds__(256) void proj_mfma_kernel(
    const unsigned short* __restrict__ xq_src, long long xq_bs,
    const unsigned short* __restrict__ xkv_src, long long xkv_bs,
    const unsigned short* __restrict__ w3,
    const float* __restrict__ bq, const float* __restrict__ bk,
    const float* __restrict__ bv,
    unsigned short* __restrict__ Qo, unsigned short* __restrict__ Ko,
    unsigned short* __restrict__ Vt)
{
    int t0 = blockIdx.x * 32, b = blockIdx.y;
    __shared__ __align__(16) unsigned short xsq[32 * 136];
    __shared__ __align__(16) unsigned short xskv[32 * 136];
    int tid = threadIdx.x;
    int wid = tid >> 6, lane = tid & 63;
    int n = lane & 15, g = lane >> 4;
    int tsub = (wid & 1) * 16, fh = (wid >> 1) * 64;

    for (int l = tid; l < 512; l += 256) {
        int r = l >> 4, cc = l & 15;
        *(u16x8*)&xsq[r * 136 + cc * 8] =
            *(const u16x8*)&xq_src[xq_bs * b + (size_t)(t0 + r) * FF + cc * 8];
        *(u16x8*)&xskv[r * 136 + cc * 8] =
            *(const u16x8*)&xkv_src[xkv_bs * b + (size_t)(t0 + r) * FF + cc * 8];
    }
    __syncthreads();

    f32x4 acc[3][4];
#pragma unroll
    for (int p = 0; p < 3; ++p)
#pragma unroll
        for (int i = 0; i < 4; ++i) acc[p][i] = (f32x4){0.f, 0.f, 0.f, 0.f};

#pragma unroll
    for (int kk = 0; kk < 4; ++kk) {
        s16x8 bxq = *(const s16x8*)&xsq[(tsub + n) * 136 + kk * 32 + g * 8];
        s16x8 bxkv = *(const s16x8*)&xskv[(tsub + n) * 136 + kk * 32 + g * 8];
#pragma unroll
        for (int i = 0; i < 4; ++i) {
            const unsigned short* wb = &w3[(size_t)(fh + i * 16 + n) * 128 + kk * 32 + g * 8];
            s16x8 a0 = *(const s16x8*)&wb[0];
            s16x8 a1 = *(const s16x8*)&wb[16384];
            s16x8 a2 = *(const s16x8*)&wb[32768];
            acc[0][i] = __builtin_amdgcn_mfma_f32_16x16x32_bf16(a0, bxq, acc[0][i], 0, 0, 0);
            acc[1][i] = __builtin_amdgcn_mfma_f32_16x16x32_bf16(a1, bxkv, acc[1][i], 0, 0, 0);
            acc[2][i] = __builtin_amdgcn_mfma_f32_16x16x32_bf16(a2, bxkv, acc[2][i], 0, 0, 0);
        }
    }

    const float scale = 0.088388347648318447f;
    int t = t0 + tsub + n;
#pragma unroll
    for (int i = 0; i < 4; ++i) {
        int fb = fh + i * 16 + g * 4;
        u16x4 pk;
#pragma unroll
        for (int r = 0; r < 4; ++r) pk[r] = f2bf(acc[0][i][r] + bq[fb + r] * scale);
        *(u16x4*)&Qo[((size_t)b * TT + t) * FF + fb] = pk;
#pragma unroll
        for (int r = 0; r < 4; ++r) pk[r] = f2bf(acc[1][i][r] + bk[fb + r]);
        *(u16x4*)&Ko[((size_t)b * TT + t) * FF + fb] = pk;
#pragma unroll
        for (int r = 0; r < 4; ++r)
            Vt[((size_t)b * FF + fb + r) * TT + t] = f2bf(acc[2][i][r] + bv[fb + r]);
    }
}

// ---------------------------------------------------------------------------
// Flash attention via MFMA.  grid (8, 32), block 256 = 4 waves.
// ---------------------------------------------------------------------------
__global__ __launch_bounds__(256) void attn_mfma_kernel(
    const unsigned short* __restrict__ Qb, const unsigned short* __restrict__ Kb,
    const unsigned short* __restrict__ Vtb,
    const float* __restrict__ orig, long long bso, int cso, int tso,
    float* __restrict__ out_tf, unsigned short* __restrict__ out_x, int xoff)
{
    __shared__ __align__(16) unsigned short Ks[64 * 136];
    __shared__ __align__(16) unsigned short Vs[128 * 72];
    __shared__ __align__(16) unsigned short Ps[4 * 16 * 68];

    int t0 = blockIdx.x * 64, b = blockIdx.y;
    int tid = threadIdx.x;
    int wid = tid >> 6, lane = tid & 63;
    int n = lane & 15, g = lane >> 4;
    int q0 = t0 + wid * 16;
    unsigned short* Pw = &Ps[wid * 1088];

    s16x8 qf[4];
#pragma unroll
    for (int kk = 0; kk < 4; ++kk)
        qf[kk] = *(const s16x8*)&Qb[((size_t)b * TT + q0 + n) * FF + kk * 32 + g * 8];

    u16x8 kst[4], vst[4];
#pragma unroll
    for (int ii = 0; ii < 4; ++ii) {
        int l = tid + 256 * ii;
        kst[ii] = *(const u16x8*)&Kb[((size_t)b * TT + (l >> 4)) * FF + (l & 15) * 8];
        vst[ii] = *(const u16x8*)&Vtb[((size_t)b * FF + (l >> 3)) * TT + (l & 7) * 8];
    }

    f32x4 O[8];
#pragma unroll
    for (int ft = 0; ft < 8; ++ft) O[ft] = (f32x4){0.f, 0.f, 0.f, 0.f};
    float m[4] = {-1e30f, -1e30f, -1e30f, -1e30f};
    float lsum[4] = {0.f, 0.f, 0.f, 0.f};

    for (int it = 0; it < 8; ++it) {
        __syncthreads();
#pragma unroll
        for (int ii = 0; ii < 4; ++ii) {
            int l = tid + 256 * ii;
            *(u16x8*)&Ks[(l >> 4) * 136 + (l & 15) * 8] = kst[ii];
            *(u16x8*)&Vs[(l >> 3) * 72 + (l & 7) * 8] = vst[ii];
        }
        __syncthreads();
        if (it < 7) {
            int s0n = (it + 1) * 64;
#pragma unroll
            for (int ii = 0; ii < 4; ++ii) {
                int l = tid + 256 * ii;
                kst[ii] = *(const u16x8*)&Kb[((size_t)b * TT + s0n + (l >> 4)) * FF + (l & 15) * 8];
                vst[ii] = *(const u16x8*)&Vtb[((size_t)b * FF + (l >> 3)) * TT + s0n + (l & 7) * 8];
            }
        }

        f32x4 acc[4];
#pragma unroll
        for (int st = 0; st < 4; ++st) acc[st] = (f32x4){0.f, 0.f, 0.f, 0.f};
#pragma unroll
        for (int kk = 0; kk < 4; ++kk) {
#pragma unroll
            for (int st = 0; st < 4; ++st) {
                s16x8 kf = *(const s16x8*)&Ks[(st * 16 + n) * 136 + kk * 32 + g * 8];
                acc[st] = __builtin_amdgcn_mfma_f32_16x16x32_bf16(qf[kk], kf, acc[st], 0, 0, 0);
            }
        }

        float mnew[4], c[4], rs[4];
#pragma unroll
        for (int r = 0; r < 4; ++r) {
            float tm = fmaxf(fmaxf(acc[0][r], acc[1][r]), fmaxf(acc[2][r], acc[3][r]));
#pragma unroll
            for (int msk = 1; msk < 16; msk <<= 1) tm = fmaxf(tm, __shfl_xor(tm, msk));
            mnew[r] = fmaxf(m[r], tm);
            c[r] = __expf(m[r] - mnew[r]);
            m[r] = mnew[r];
            rs[r] = 0.f;
        }
#pragma unroll
        for (int st = 0; st < 4; ++st) {
#pragma unroll
            for (int r = 0; r < 4; ++r) {
                float p = __expf(acc[st][r] - mnew[r]);
                rs[r] += p;
                Pw[(g * 4 + r) * 68 + st * 16 + n] = f2bf(p);
            }
        }
#pragma unroll
        for (int r = 0; r < 4; ++r) {
#pragma unroll
            for (int msk = 1; msk < 16; msk <<= 1) rs[r] += __shfl_xor(rs[r], msk);
            lsum[r] = lsum[r] * c[r] + rs[r];
        }
#pragma unroll
        for (int ft = 0; ft < 8; ++ft) {
#pragma unroll
            for (int r = 0; r < 4; ++r) O[ft][r] *= c[r];
        }

#pragma unroll
        for (int ks = 0; ks < 2; ++ks) {
            s16x8 pf = *(const s16x8*)&Pw[n * 68 + ks * 32 + g * 8];
#pragma unroll
            for (int ft = 0; ft < 8; ++ft) {
                s16x8 vf = *(const s16x8*)&Vs[(ft * 16 + n) * 72 + ks * 32 + g * 8];
                O[ft] = __builtin_amdgcn_mfma_f32_16x16x32_bf16(pf, vf, O[ft], 0, 0, 0);
            }
        }
    }

    float rinv[4];
#pragma unroll
    for (int r = 0; r < 4; ++r) rinv[r] = 1.f / lsum[r];
#pragma unroll
    for (int ft = 0; ft < 8; ++ft) {
        int f = ft * 16 + n;
#pragma unroll
        for (int r = 0; r < 4; ++r) {
            int q = q0 + g * 4 + r;
            float val = O[ft][r] * rinv[r];
            float xv = orig[bso * b + (size_t)f * cso + (size_t)q * tso];
            float res = val * xv + xv;
            out_tf[((size_t)b * TT + q) * FF + f] = res;
            out_x[((size_t)b * TP + xoff + q) * FF + f] = f2bf(res);
        }
    }
}

// ---------------------------------------------------------------------------
// MMD partials per timepoint (fp32 exact).
// ---------------------------------------------------------------------------
__global__ __launch_bounds__(256) void mmd_kernel(
    const float* __restrict__ f1, const float* __restrict__ f2,
    float* __restrict__ partials)
{
    int t = blockIdx.x;
    __shared__ float v1[32][129], v2[32][129];
    __shared__ float red[256];
    int tid = threadIdx.x;
    for (int l = tid; l < 4096; l += 256) {
        int i = l >> 7, f = l & 127;
        v1[i][f] = f1[((size_t)i * TT + t) * FF + f];
        v2[i][f] = f2[((size_t)i * TT + t) * FF + f];
    }
    __syncthreads();
    float s = 0.f;
    for (int r = 0; r < 4; ++r) {
        int p = tid + 256 * r;
        int i = p >> 5, j = p & 31;
        float dxx = 0.f, dyy = 0.f, dxy = 0.f;
        for (int f = 0; f < 128; ++f) {
            float a = v1[i][f], b_ = v1[j][f], c = v2[i][f], d = v2[j][f];
            float e1 = a - b_, e2 = c - d, e3 = a - d;
            dxx += e1 * e1; dyy += e2 * e2; dxy += e3 * e3;
        }
        s += __expf(-0.5f * dxx) + __expf(-0.5f * dyy) - 2.f * __expf(-0.5f * dxy);
    }
    red[tid] = s;
    __syncthreads();
    for (int off = 128; off; off >>= 1) {
        if (tid < off) red[tid] += red[tid + off];
        __syncthreads();
    }
    if (tid == 0) partials[t] = red[0];
}

// ---------------------------------------------------------------------------
// TCN layer via MFMA, 64o x 64t wave tile, weights + x staged in LDS,
// load-early/write-late.  x bf16 [b][t][Cin]; w4 bf16 [4][256][Cin];
// out bf16 [b][t][256].  grid (4 t-tiles of 256, 4 o-tiles, 32 b),
// block 256 = 4 waves stacked in t; wave = 64o x 64t (4i x 4j).
// do_pool: reduce sum over t into pool_out [b][4 tslices][256].
// ---------------------------------------------------------------------------
__global__ __launch_bounds__(256, 2) void tcn_mfma_kernel(
    const unsigned short* __restrict__ x, int Cin, int d,
    const unsigned short* __restrict__ w4,
    const float* __restrict__ cb, const float* __restrict__ rb,
    unsigned short* __restrict__ out, float* __restrict__ pool_out, int do_pool)
{
    int t0 = blockIdx.x * 256, o0 = blockIdx.y * 64, b = blockIdx.z;
    __shared__ __align__(16) unsigned short xs[264 * 40];     // [row][c] pitch 40
    __shared__ __align__(16) unsigned short wsh[4 * 64 * 40]; // [plane][o][c]
    __shared__ float pool_s[4][64];
    int tid = threadIdx.x;
    int wid = tid >> 6, lane = tid & 63;
    int n = lane & 15, g = lane >> 4;
    int wt = wid * 64;              // wave's t offset in block tile
    int d2 = 2 * d;
    int nrow = 256 + d2;            // <= 264
    const unsigned short* xb = x + (size_t)b * TP * Cin;

    // staging geometry: thread covers x rows (tid>>2)+{0,64,128,192}(+256),
    // and w o-row (tid>>2) for 4 planes; gg = c-subblock.
    int gg = tid & 3;
    int xr0 = tid >> 2;             // 0..63
    int tg0 = t0 - d2 + xr0;        // only this may be < 0 (t0 == 0)
    bool xv4 = xr0 < d2;            // rows 256..256+d2-1
    const unsigned short* wbase = w4 + (size_t)(o0 + (tid >> 2)) * Cin + gg * 8;
    size_t wps = (size_t)256 * Cin;

    u16x8 sx0, sx1, sx2, sx3, sx4, sw0, sw1, sw2, sw3;
    const u16x8 zz = {0, 0, 0, 0, 0, 0, 0, 0};
#define LDST(C0)                                                               \
    do {                                                                       \
        sx0 = (tg0 >= 0) ? *(const u16x8*)&xb[(size_t)tg0 * Cin + (C0) + gg * 8] : zz; \
        sx1 = *(const u16x8*)&xb[(size_t)(tg0 + 64) * Cin + (C0) + gg * 8];    \
        sx2 = *(const u16x8*)&xb[(size_t)(tg0 + 128) * Cin + (C0) + gg * 8];   \
        sx3 = *(const u16x8*)&xb[(size_t)(tg0 + 192) * Cin + (C0) + gg * 8];   \
        sx4 = xv4 ? *(const u16x8*)&xb[(size_t)(tg0 + 256) * Cin + (C0) + gg * 8] : zz; \
        sw0 = *(const u16x8*)&wbase[(C0)];                                     \
        sw1 = *(const u16x8*)&wbase[wps + (C0)];                               \
        sw2 = *(const u16x8*)&wbase[2 * wps + (C0)];                           \
        sw3 = *(const u16x8*)&wbase[3 * wps + (C0)];                           \
    } while (0)

    f32x4 accc[4][4], accr[4][4];
#pragma unroll
    for (int i = 0; i < 4; ++i)
#pragma unroll
        for (int j = 0; j < 4; ++j) {
            accc[i][j] = (f32x4){0.f, 0.f, 0.f, 0.f};
            accr[i][j] = (f32x4){0.f, 0.f, 0.f, 0.f};
        }

    LDST(0);
    for (int c0 = 0; c0 < Cin; c0 += 32) {
        __syncthreads();   // previous slice's LDS reads complete
        *(u16x8*)&xs[xr0 * 40 + gg * 8] = sx0;
        *(u16x8*)&xs[(xr0 + 64) * 40 + gg * 8] = sx1;
        *(u16x8*)&xs[(xr0 + 128) * 40 + gg * 8] = sx2;
        *(u16x8*)&xs[(xr0 + 192) * 40 + gg * 8] = sx3;
        if (xv4) *(u16x8*)&xs[(xr0 + 256) * 40 + gg * 8] = sx4;
        {
            int wrow = (tid >> 2) * 40 + gg * 8;
            *(u16x8*)&wsh[wrow] = sw0;
            *(u16x8*)&wsh[2560 + wrow] = sw1;
            *(u16x8*)&wsh[5120 + wrow] = sw2;
            *(u16x8*)&wsh[7680 + wrow] = sw3;
        }
        __syncthreads();
        if (c0 + 32 < Cin) LDST(c0 + 32);   // prefetch next slice into regs

        // B-fragments (x) read once, reused across all 4 o sub-tiles
        s16x8 bfr[4][3];
#pragma unroll
        for (int j = 0; j < 4; ++j) {
            int tl = wt + j * 16 + n;
#pragma unroll
            for (int k = 0; k < 3; ++k)
                bfr[j][k] = *(const s16x8*)&xs[(tl + k * d) * 40 + g * 8];
        }
#pragma unroll
        for (int i = 0; i < 4; ++i) {
            int wrow = (i * 16 + n) * 40 + g * 8;
            s16x8 a0 = *(const s16x8*)&wsh[wrow];
            s16x8 a1 = *(const s16x8*)&wsh[2560 + wrow];
            s16x8 a2 = *(const s16x8*)&wsh[5120 + wrow];
            s16x8 ar = *(const s16x8*)&wsh[7680 + wrow];
#pragma unroll
            for (int j = 0; j < 4; ++j) {
                accc[i][j] = __builtin_amdgcn_mfma_f32_16x16x32_bf16(a0, bfr[j][0], accc[i][j], 0, 0, 0);
                accc[i][j] = __builtin_amdgcn_mfma_f32_16x16x32_bf16(a1, bfr[j][1], accc[i][j], 0, 0, 0);
                accc[i][j] = __builtin_amdgcn_mfma_f32_16x16x32_bf16(a2, bfr[j][2], accc[i][j], 0, 0, 0);
                accr[i][j] = __builtin_amdgcn_mfma_f32_16x16x32_bf16(ar, bfr[j][2], accr[i][j], 0, 0, 0);
            }
        }
    }
#undef LDST

    // epilogue: D row (o-local) = g*4 + reg, col (t-local) = n
#pragma unroll
    for (int i = 0; i < 4; ++i) {
        int ob = o0 + i * 16 + g * 4;
        float cbv0 = cb[ob], cbv1 = cb[ob + 1], cbv2 = cb[ob + 2], cbv3 = cb[ob + 3];
        float rbv0 = rb[ob], rbv1 = rb[ob + 1], rbv2 = rb[ob + 2], rbv3 = rb[ob + 3];
        float ps0 = 0.f, ps1 = 0.f, ps2 = 0.f, ps3 = 0.f;
#pragma unroll
        for (int j = 0; j < 4; ++j) {
            int t = t0 + wt + j * 16 + n;
            float v0 = fmaxf(accc[i][j][0] + cbv0, 0.f) + accr[i][j][0] + rbv0;
            float v1 = fmaxf(accc[i][j][1] + cbv1, 0.f) + accr[i][j][1] + rbv1;
            float v2 = fmaxf(accc[i][j][2] + cbv2, 0.f) + accr[i][j][2] + rbv2;
            float v3 = fmaxf(accc[i][j][3] + cbv3, 0.f) + accr[i][j][3] + rbv3;
            ps0 += v0; ps1 += v1; ps2 += v2; ps3 += v3;
            if (!do_pool) {
                u16x4 pk;
                pk[0] = f2bf(v0); pk[1] = f2bf(v1); pk[2] = f2bf(v2); pk[3] = f2bf(v3);
                *(u16x4*)&out[((size_t)b * TP + t) * HID + ob] = pk;
            }
        }
        if (do_pool) {
#pragma unroll
            for (int msk = 1; msk < 16; msk <<= 1) {
                ps0 += __shfl_xor(ps0, msk);
                ps1 += __shfl_xor(ps1, msk);
                ps2 += __shfl_xor(ps2, msk);
                ps3 += __shfl_xor(ps3, msk);
            }
            if (n == 0) {
                int ol = i * 16 + g * 4;
                pool_s[wid][ol + 0] = ps0;
                pool_s[wid][ol + 1] = ps1;
                pool_s[wid][ol + 2] = ps2;
                pool_s[wid][ol + 3] = ps3;
            }
        }
    }
    if (do_pool) {
        __syncthreads();
        if (tid < 64) {
            float s = pool_s[0][tid] + pool_s[1][tid] + pool_s[2][tid] + pool_s[3][tid];
            pool_out[((size_t)b * 4 + blockIdx.x) * HID + o0 + tid] = s;
        }
    }
}

// ---------------------------------------------------------------------------
// final: fc on pooled sums (4 t-slices) + MMD reduce.
// ---------------------------------------------------------------------------
__global__ __launch_bounds__(256) void final_kernel(
    const float* __restrict__ pp, const float* __restrict__ fcw,
    const float* __restrict__ fcb, const float* __restrict__ partials,
    float* __restrict__ dout)
{
    int tid = threadIdx.x;
    if (tid < 128) {
        int b = tid >> 2, k = tid & 3;
        float s = 0.f;
        for (int c = 0; c < HID; ++c) {
            float pc = 0.f;
#pragma unroll
            for (int xs = 0; xs < 4; ++xs) pc += pp[((size_t)b * 4 + xs) * HID + c];
            s += pc * fcw[k * HID + c];
        }
        dout[tid] = fcb[k] + s * (1.f / 1024.f);
    } else if (tid < 192) {
        int lane = tid - 128;
        float s = 0.f;
        for (int j = 0; j < 8; ++j) s += partials[lane + 64 * j];
        for (int off = 32; off; off >>= 1) s += __shfl_down(s, off);
        if (lane == 0) dout[128] = s * (1.f / (32.f * 32.f * 512.f));
    }
}

// ---------------------------------------------------------------------------
extern "C" void kernel_launch(void* const* d_in, const int* in_sizes, int n_in,
                              void* d_out, int out_size, void* d_ws, size_t ws_size,
                              hipStream_t stream)
{
    const float* feat1 = (const float*)d_in[0];
    const float* feat2 = (const float*)d_in[1];
    const float* wq_a = (const float*)d_in[2];
    const float* bq_a = (const float*)d_in[3];
    const float* wk_a = (const float*)d_in[4];
    const float* bk_a = (const float*)d_in[5];
    const float* wv_a = (const float*)d_in[6];
    const float* bv_a = (const float*)d_in[7];
    const float* wq_b = (const float*)d_in[8];
    const float* bq_b = (const float*)d_in[9];
    const float* wk_b = (const float*)d_in[10];
    const float* bk_b = (const float*)d_in[11];
    const float* wv_b = (const float*)d_in[12];
    const float* bv_b = (const float*)d_in[13];
    const float* cw0 = (const float*)d_in[14];
    const float* cb0 = (const float*)d_in[15];
    const float* rw0 = (const float*)d_in[16];
    const float* rb0 = (const float*)d_in[17];
    const float* cw1 = (const float*)d_in[18];
    const float* cb1 = (const float*)d_in[19];
    const float* rw1 = (const float*)d_in[20];
    const float* rb1 = (const float*)d_in[21];
    const float* cw2 = (const float*)d_in[22];
    const float* cb2 = (const float*)d_in[23];
    const float* rw2 = (const float*)d_in[24];
    const float* rb2 = (const float*)d_in[25];
    const float* fcw = (const float*)d_in[26];
    const float* fcb = (const float*)d_in[27];
    float* dout = (float*)d_out;

    // workspace layout (float offsets):
    //   Qbf @ 0 (1048576), Kbf @ 1048576, Vt @ 2097152
    //   f1tf @ 3145728 (fp32 2097152), f2tf @ 5242880
    //   xbuf @ 7340032 (bf16 [32][1024][128])
    //   wbuf @ 9437184 (tcn bf16 planes, 327680 floats)
    //   xbf1 @ 9798144, xbf2 @ 10846720 (bf16 inputs)
    //   qkvw @ 11895296 (49152 floats)
    //   poolpart @ 11944448 (32*4*256 = 32768 floats)
    //   mmdpart @ 11977216 (512)
    //   h_a aliases 0..4194304 ; h_b aliases 4194304..8388608
    float* ws = (float*)d_ws;
    unsigned short* Qbf = (unsigned short*)ws;
    unsigned short* Kbf = (unsigned short*)(ws + 1048576);
    unsigned short* Vt  = (unsigned short*)(ws + 2097152);
    float* f1tf = ws + 3145728;
    float* f2tf = ws + 5242880;
    unsigned short* xbuf = (unsigned short*)(ws + 7340032);
    unsigned short* wbuf = (unsigned short*)(ws + 9437184);
    unsigned short* wb0 = wbuf;
    unsigned short* wb1 = wbuf + 131072;
    unsigned short* wb2 = wbuf + 393216;
    unsigned short* xbf1 = (unsigned short*)(ws + 9798144);
    unsigned short* xbf2 = (unsigned short*)(ws + 10846720);
    unsigned short* qkvw = (unsigned short*)(ws + 11895296);
    unsigned short* w3a = qkvw;
    unsigned short* w3b = qkvw + 3 * 16384;
    float* poolpart = ws + 11944448;
    float* mmdpart  = ws + 11977216;
    unsigned short* h_a = (unsigned short*)ws;
    unsigned short* h_b = (unsigned short*)(ws + 4194304);

    // prep: transpose-convert both features; convert all weights
    t2bf_kernel<<<dim3(16, 4, 64), 256, 0, stream>>>(feat1, feat2, xbf1, xbf2);
    prep_all_kernel<<<dim3(2944), 256, 0, stream>>>(
        wq_a, wk_a, wv_a, wq_b, wk_b, wv_b,
        cw0, rw0, cw1, rw1, cw2, rw2, qkvw, wb0, wb1, wb2);

    // branch A: Q from feat2 (xbf2), K/V from feat1 (xbf1)
    proj_mfma_kernel<<<dim3(16, 32), 256, 0, stream>>>(
        xbf2, (long long)TT * FF, xbf1, (long long)TT * FF, w3a,
        bq_a, bk_a, bv_a, Qbf, Kbf, Vt);
    attn_mfma_kernel<<<dim3(8, 32), 256, 0, stream>>>(
        Qbf, Kbf, Vt, feat1, 65536LL, 512, 1, f1tf, xbuf, 0);

    // branch B: Q from updated f1 (xbuf rows 0..511), K/V from feat2 (xbf2)
    proj_mfma_kernel<<<dim3(16, 32), 256, 0, stream>>>(
        xbuf, (long long)TP * FF, xbf2, (long long)TT * FF, w3b,
        bq_b, bk_b, bv_b, Qbf, Kbf, Vt);
    attn_mfma_kernel<<<dim3(8, 32), 256, 0, stream>>>(
        Qbf, Kbf, Vt, feat2, 65536LL, 512, 1, f2tf, xbuf, 512);

    // MMD partials (before TCN overwrites f1tf/f2tf regions)
    mmd_kernel<<<dim3(512), 256, 0, stream>>>(f1tf, f2tf, mmdpart);

    // TCN stack: xbuf(128ch) -> h_a -> h_b -> pooled (fused)
    tcn_mfma_kernel<<<dim3(4, 4, 32), 256, 0, stream>>>(xbuf, 128, 1, wb0, cb0, rb0, h_a, nullptr, 0);
    tcn_mfma_kernel<<<dim3(4, 4, 32), 256, 0, stream>>>(h_a, 256, 2, wb1, cb1, rb1, h_b, nullptr, 0);
    tcn_mfma_kernel<<<dim3(4, 4, 32), 256, 0, stream>>>(h_b, 256, 4, wb2, cb2, rb2, h_a, poolpart, 1);

    final_kernel<<<dim3(1), 256, 0, stream>>>(poolpart, fcw, fcb, mmdpart, dout);
}

// Round 8
// 182.739 us; speedup vs baseline: 1.8332x; 1.0864x over previous
//
#include <hip/hip_runtime.h>

#define BB 32
#define TT 512
#define FF 128
#define HID 256
#define TP 1024

typedef __attribute__((ext_vector_type(8))) short s16x8;
typedef __attribute__((ext_vector_type(8))) unsigned short u16x8;
typedef __attribute__((ext_vector_type(4))) unsigned short u16x4;
typedef __attribute__((ext_vector_type(4))) float f32x4;

static __device__ __forceinline__ unsigned short f2bf(float f) {
    unsigned u = __builtin_bit_cast(unsigned, f);
    u = (u + 0x7FFFu + ((u >> 16) & 1u)) >> 16;
    return (unsigned short)u;
}
static __device__ __forceinline__ float bf2f(unsigned short b) {
    return __builtin_bit_cast(float, ((unsigned)b) << 16);
}

// ---------------------------------------------------------------------------
// All weight prep in one launch.
//   [0, 98304):        qkvw bf16 [6][128][128], planes 0,3 pre-scaled
//   [98304, 229376):   tcn w0 (Cin=128)
//   [229376, 491520):  tcn w1 (Cin=256)
//   [491520, 753664):  tcn w2 (Cin=256)
// ---------------------------------------------------------------------------
static __device__ __forceinline__ void tcnw_prep(
    int idx, const float* __restrict__ cw, const float* __restrict__ rw,
    unsigned short* __restrict__ out, int Cin)
{
    int p = idx / (256 * Cin);
    int rem = idx - p * 256 * Cin;
    int o = rem / Cin, c = rem - o * Cin;
    float v = (p < 3) ? cw[(o * Cin + c) * 3 + p] : rw[o * Cin + c];
    out[idx] = f2bf(v);
}

__global__ __launch_bounds__(256) void prep_all_kernel(
    const float* __restrict__ wqa, const float* __restrict__ wka,
    const float* __restrict__ wva, const float* __restrict__ wqb,
    const float* __restrict__ wkb, const float* __restrict__ wvb,
    const float* __restrict__ cw0, const float* __restrict__ rw0,
    const float* __restrict__ cw1, const float* __restrict__ rw1,
    const float* __restrict__ cw2, const float* __restrict__ rw2,
    unsigned short* __restrict__ qkvw, unsigned short* __restrict__ wb0,
    unsigned short* __restrict__ wb1, unsigned short* __restrict__ wb2)
{
    int idx = blockIdx.x * 256 + threadIdx.x;
    if (idx < 98304) {
        int p = idx >> 14, rc = idx & 16383;
        const float* srcs[6] = {wqa, wka, wva, wqb, wkb, wvb};
        float v = srcs[p][rc];
        if (p == 0 || p == 3) v *= 0.088388347648318447f;
        qkvw[idx] = f2bf(v);
    } else if (idx < 229376) {
        tcnw_prep(idx - 98304, cw0, rw0, wb0, 128);
    } else if (idx < 491520) {
        tcnw_prep(idx - 229376, cw1, rw1, wb1, 256);
    } else if (idx < 753664) {
        tcnw_prep(idx - 491520, cw2, rw2, wb2, 256);
    }
}

// ---------------------------------------------------------------------------
// QKV projection via MFMA.  x sources staged to LDS with mode:
//   mode 0: fp32 [b][128][512] (c-major), batch stride in floats
//   mode 1: bf16 [b][t][128]   (t-major), batch stride in u16
// grid (16, 32), block 256 = 4 waves.
// ---------------------------------------------------------------------------
__global__ __launch_bounds__(256) void proj_mfma_kernel(
    const void* __restrict__ xq_src, int xq_mode, long long xq_bs,
    const void* __restrict__ xkv_src, int xkv_mode, long long xkv_bs,
    const unsigned short* __restrict__ w3,
    const float* __restrict__ bq, const float* __restrict__ bk,
    const float* __restrict__ bv,
    unsigned short* __restrict__ Qo, unsigned short* __restrict__ Ko,
    unsigned short* __restrict__ Vt)
{
    int t0 = blockIdx.x * 32, b = blockIdx.y;
    __shared__ __align__(16) unsigned short xsq[32 * 136];
    __shared__ __align__(16) unsigned short xskv[32 * 136];
    int tid = threadIdx.x;
    int wid = tid >> 6, lane = tid & 63;
    int n = lane & 15, g = lane >> 4;
    int tsub = (wid & 1) * 16, fh = (wid >> 1) * 64;

    if (xq_mode == 0) {
        const float* s = (const float*)xq_src + (size_t)b * xq_bs;
        for (int l = tid; l < 4096; l += 256) {
            int c = l >> 5, tt = l & 31;
            xsq[tt * 136 + c] = f2bf(s[(size_t)c * TT + t0 + tt]);
        }
    } else {
        const unsigned short* s = (const unsigned short*)xq_src + (size_t)b * xq_bs;
        for (int l = tid; l < 512; l += 256) {
            int r = l >> 4, cc = l & 15;
            *(u16x8*)&xsq[r * 136 + cc * 8] = *(const u16x8*)&s[(size_t)(t0 + r) * FF + cc * 8];
        }
    }
    if (xkv_mode == 0) {
        const float* s = (const float*)xkv_src + (size_t)b * xkv_bs;
        for (int l = tid; l < 4096; l += 256) {
            int c = l >> 5, tt = l & 31;
            xskv[tt * 136 + c] = f2bf(s[(size_t)c * TT + t0 + tt]);
        }
    } else {
        const unsigned short* s = (const unsigned short*)xkv_src + (size_t)b * xkv_bs;
        for (int l = tid; l < 512; l += 256) {
            int r = l >> 4, cc = l & 15;
            *(u16x8*)&xskv[r * 136 + cc * 8] = *(const u16x8*)&s[(size_t)(t0 + r) * FF + cc * 8];
        }
    }
    __syncthreads();

    f32x4 acc[3][4];
#pragma unroll
    for (int p = 0; p < 3; ++p)
#pragma unroll
        for (int i = 0; i < 4; ++i) acc[p][i] = (f32x4){0.f, 0.f, 0.f, 0.f};

#pragma unroll
    for (int kk = 0; kk < 4; ++kk) {
        s16x8 bxq = *(const s16x8*)&xsq[(tsub + n) * 136 + kk * 32 + g * 8];
        s16x8 bxkv = *(const s16x8*)&xskv[(tsub + n) * 136 + kk * 32 + g * 8];
#pragma unroll
        for (int i = 0; i < 4; ++i) {
            const unsigned short* wb = &w3[(size_t)(fh + i * 16 + n) * 128 + kk * 32 + g * 8];
            s16x8 a0 = *(const s16x8*)&wb[0];
            s16x8 a1 = *(const s16x8*)&wb[16384];
            s16x8 a2 = *(const s16x8*)&wb[32768];
            acc[0][i] = __builtin_amdgcn_mfma_f32_16x16x32_bf16(a0, bxq, acc[0][i], 0, 0, 0);
            acc[1][i] = __builtin_amdgcn_mfma_f32_16x16x32_bf16(a1, bxkv, acc[1][i], 0, 0, 0);
            acc[2][i] = __builtin_amdgcn_mfma_f32_16x16x32_bf16(a2, bxkv, acc[2][i], 0, 0, 0);
        }
    }

    const float scale = 0.088388347648318447f;
    int t = t0 + tsub + n;
#pragma unroll
    for (int i = 0; i < 4; ++i) {
        int fb = fh + i * 16 + g * 4;
        u16x4 pk;
#pragma unroll
        for (int r = 0; r < 4; ++r) pk[r] = f2bf(acc[0][i][r] + bq[fb + r] * scale);
        *(u16x4*)&Qo[((size_t)b * TT + t) * FF + fb] = pk;
#pragma unroll
        for (int r = 0; r < 4; ++r) pk[r] = f2bf(acc[1][i][r] + bk[fb + r]);
        *(u16x4*)&Ko[((size_t)b * TT + t) * FF + fb] = pk;
#pragma unroll
        for (int r = 0; r < 4; ++r)
            Vt[((size_t)b * FF + fb + r) * TT + t] = f2bf(acc[2][i][r] + bv[fb + r]);
    }
}

// ---------------------------------------------------------------------------
// Flash attention via MFMA.  grid (8, 32), block 256 = 4 waves.
// ---------------------------------------------------------------------------
__global__ __launch_bounds__(256) void attn_mfma_kernel(
    const unsigned short* __restrict__ Qb, const unsigned short* __restrict__ Kb,
    const unsigned short* __restrict__ Vtb,
    const float* __restrict__ orig, long long bso, int cso, int tso,
    float* __restrict__ out_tf, unsigned short* __restrict__ out_x, int xoff)
{
    __shared__ __align__(16) unsigned short Ks[64 * 136];
    __shared__ __align__(16) unsigned short Vs[128 * 72];
    __shared__ __align__(16) unsigned short Ps[4 * 16 * 68];

    int t0 = blockIdx.x * 64, b = blockIdx.y;
    int tid = threadIdx.x;
    int wid = tid >> 6, lane = tid & 63;
    int n = lane & 15, g = lane >> 4;
    int q0 = t0 + wid * 16;
    unsigned short* Pw = &Ps[wid * 1088];

    s16x8 qf[4];
#pragma unroll
    for (int kk = 0; kk < 4; ++kk)
        qf[kk] = *(const s16x8*)&Qb[((size_t)b * TT + q0 + n) * FF + kk * 32 + g * 8];

    u16x8 kst[4], vst[4];
#pragma unroll
    for (int ii = 0; ii < 4; ++ii) {
        int l = tid + 256 * ii;
        kst[ii] = *(const u16x8*)&Kb[((size_t)b * TT + (l >> 4)) * FF + (l & 15) * 8];
        vst[ii] = *(const u16x8*)&Vtb[((size_t)b * FF + (l >> 3)) * TT + (l & 7) * 8];
    }

    f32x4 O[8];
#pragma unroll
    for (int ft = 0; ft < 8; ++ft) O[ft] = (f32x4){0.f, 0.f, 0.f, 0.f};
    float m[4] = {-1e30f, -1e30f, -1e30f, -1e30f};
    float lsum[4] = {0.f, 0.f, 0.f, 0.f};

    for (int it = 0; it < 8; ++it) {
        __syncthreads();
#pragma unroll
        for (int ii = 0; ii < 4; ++ii) {
            int l = tid + 256 * ii;
            *(u16x8*)&Ks[(l >> 4) * 136 + (l & 15) * 8] = kst[ii];
            *(u16x8*)&Vs[(l >> 3) * 72 + (l & 7) * 8] = vst[ii];
        }
        __syncthreads();
        if (it < 7) {
            int s0n = (it + 1) * 64;
#pragma unroll
            for (int ii = 0; ii < 4; ++ii) {
                int l = tid + 256 * ii;
                kst[ii] = *(const u16x8*)&Kb[((size_t)b * TT + s0n + (l >> 4)) * FF + (l & 15) * 8];
                vst[ii] = *(const u16x8*)&Vtb[((size_t)b * FF + (l >> 3)) * TT + s0n + (l & 7) * 8];
            }
        }

        f32x4 acc[4];
#pragma unroll
        for (int st = 0; st < 4; ++st) acc[st] = (f32x4){0.f, 0.f, 0.f, 0.f};
        __builtin_amdgcn_s_setprio(1);
#pragma unroll
        for (int kk = 0; kk < 4; ++kk) {
#pragma unroll
            for (int st = 0; st < 4; ++st) {
                s16x8 kf = *(const s16x8*)&Ks[(st * 16 + n) * 136 + kk * 32 + g * 8];
                acc[st] = __builtin_amdgcn_mfma_f32_16x16x32_bf16(qf[kk], kf, acc[st], 0, 0, 0);
            }
        }
        __builtin_amdgcn_s_setprio(0);

        float mnew[4], c[4], rs[4];
#pragma unroll
        for (int r = 0; r < 4; ++r) {
            float tm = fmaxf(fmaxf(acc[0][r], acc[1][r]), fmaxf(acc[2][r], acc[3][r]));
#pragma unroll
            for (int msk = 1; msk < 16; msk <<= 1) tm = fmaxf(tm, __shfl_xor(tm, msk));
            mnew[r] = fmaxf(m[r], tm);
            c[r] = __expf(m[r] - mnew[r]);
            m[r] = mnew[r];
            rs[r] = 0.f;
        }
#pragma unroll
        for (int st = 0; st < 4; ++st) {
#pragma unroll
            for (int r = 0; r < 4; ++r) {
                float p = __expf(acc[st][r] - mnew[r]);
                rs[r] += p;
                Pw[(g * 4 + r) * 68 + st * 16 + n] = f2bf(p);
            }
        }
#pragma unroll
        for (int r = 0; r < 4; ++r) {
#pragma unroll
            for (int msk = 1; msk < 16; msk <<= 1) rs[r] += __shfl_xor(rs[r], msk);
            lsum[r] = lsum[r] * c[r] + rs[r];
        }
#pragma unroll
        for (int ft = 0; ft < 8; ++ft) {
#pragma unroll
            for (int r = 0; r < 4; ++r) O[ft][r] *= c[r];
        }

        __builtin_amdgcn_s_setprio(1);
#pragma unroll
        for (int ks = 0; ks < 2; ++ks) {
            s16x8 pf = *(const s16x8*)&Pw[n * 68 + ks * 32 + g * 8];
#pragma unroll
            for (int ft = 0; ft < 8; ++ft) {
                s16x8 vf = *(const s16x8*)&Vs[(ft * 16 + n) * 72 + ks * 32 + g * 8];
                O[ft] = __builtin_amdgcn_mfma_f32_16x16x32_bf16(pf, vf, O[ft], 0, 0, 0);
            }
        }
        __builtin_amdgcn_s_setprio(0);
    }

    float rinv[4];
#pragma unroll
    for (int r = 0; r < 4; ++r) rinv[r] = 1.f / lsum[r];
#pragma unroll
    for (int ft = 0; ft < 8; ++ft) {
        int f = ft * 16 + n;
#pragma unroll
        for (int r = 0; r < 4; ++r) {
            int q = q0 + g * 4 + r;
            float val = O[ft][r] * rinv[r];
            float xv = orig[bso * b + (size_t)f * cso + (size_t)q * tso];
            float res = val * xv + xv;
            out_tf[((size_t)b * TT + q) * FF + f] = res;
            out_x[((size_t)b * TP + xoff + q) * FF + f] = f2bf(res);
        }
    }
}

// ---------------------------------------------------------------------------
// MMD partials per timepoint via split-precision MFMA Gram matrices.
// d(i,j) = G[i,i] + G[j,j] - 2 G[i,j]; G = Xhi.Xhi^T + Xhi.Xlo^T + Xlo.Xhi^T.
// Diagonal cancels exactly; off-diagonal error ~1e-4 on exp(-large) ~ 0.
// grid (512), block 256 = 4 waves; wave computes 3 of 12 (gram, quadrant) units.
// ---------------------------------------------------------------------------
__global__ __launch_bounds__(256) void mmd_kernel(
    const float* __restrict__ f1, const float* __restrict__ f2,
    float* __restrict__ partials)
{
    int t = blockIdx.x;
    __shared__ __align__(16) unsigned short X1h[32 * 136], X1l[32 * 136];
    __shared__ __align__(16) unsigned short X2h[32 * 136], X2l[32 * 136];
    __shared__ float Gs[3][32][33];
    __shared__ float red[256];
    int tid = threadIdx.x;

    for (int l = tid; l < 4096; l += 256) {
        int i = l >> 7, f = l & 127;
        float v1 = f1[((size_t)i * TT + t) * FF + f];
        float v2 = f2[((size_t)i * TT + t) * FF + f];
        unsigned short h1 = f2bf(v1);
        unsigned short h2 = f2bf(v2);
        X1h[i * 136 + f] = h1;
        X1l[i * 136 + f] = f2bf(v1 - bf2f(h1));
        X2h[i * 136 + f] = h2;
        X2l[i * 136 + f] = f2bf(v2 - bf2f(h2));
    }
    __syncthreads();

    int wid = tid >> 6, lane = tid & 63;
    int n = lane & 15, g = lane >> 4;
#pragma unroll
    for (int uu = 0; uu < 3; ++uu) {
        int u = wid * 3 + uu;
        int gram = u >> 2, quad = u & 3;
        int qi = quad >> 1, qj = quad & 1;
        const unsigned short* Ah = (gram == 1) ? X2h : X1h;
        const unsigned short* Al = (gram == 1) ? X2l : X1l;
        const unsigned short* Bh = (gram == 0) ? X1h : X2h;
        const unsigned short* Bl = (gram == 0) ? X1l : X2l;
        f32x4 acc = (f32x4){0.f, 0.f, 0.f, 0.f};
#pragma unroll
        for (int kk = 0; kk < 4; ++kk) {
            int ao = (qi * 16 + n) * 136 + kk * 32 + g * 8;
            int bo = (qj * 16 + n) * 136 + kk * 32 + g * 8;
            s16x8 ah = *(const s16x8*)&Ah[ao];
            s16x8 al = *(const s16x8*)&Al[ao];
            s16x8 bh = *(const s16x8*)&Bh[bo];
            s16x8 bl = *(const s16x8*)&Bl[bo];
            acc = __builtin_amdgcn_mfma_f32_16x16x32_bf16(ah, bh, acc, 0, 0, 0);
            acc = __builtin_amdgcn_mfma_f32_16x16x32_bf16(ah, bl, acc, 0, 0, 0);
            acc = __builtin_amdgcn_mfma_f32_16x16x32_bf16(al, bh, acc, 0, 0, 0);
        }
        // D: row (A-side i) = g*4 + r, col (B-side j) = n
#pragma unroll
        for (int r = 0; r < 4; ++r)
            Gs[gram][qi * 16 + g * 4 + r][qj * 16 + n] = acc[r];
    }
    __syncthreads();

    float s = 0.f;
#pragma unroll
    for (int r = 0; r < 4; ++r) {
        int p = tid + 256 * r;
        int i = p >> 5, j = p & 31;
        float d11 = Gs[0][i][i] + Gs[0][j][j] - 2.f * Gs[0][i][j];
        float d22 = Gs[1][i][i] + Gs[1][j][j] - 2.f * Gs[1][i][j];
        float d12 = Gs[0][i][i] + Gs[1][j][j] - 2.f * Gs[2][i][j];
        s += __expf(-0.5f * d11) + __expf(-0.5f * d22) - 2.f * __expf(-0.5f * d12);
    }
    red[tid] = s;
    __syncthreads();
    for (int off = 128; off; off >>= 1) {
        if (tid < off) red[tid] += red[tid + off];
        __syncthreads();
    }
    if (tid == 0) partials[t] = red[0];
}

// ---------------------------------------------------------------------------
// TCN layer via MFMA, 64o x 64t wave tile, weights + x staged in LDS,
// load-early/write-late.  grid (4, 4, 32), block 256 = 4 waves.
// ---------------------------------------------------------------------------
__global__ __launch_bounds__(256, 2) void tcn_mfma_kernel(
    const unsigned short* __restrict__ x, int Cin, int d,
    const unsigned short* __restrict__ w4,
    const float* __restrict__ cb, const float* __restrict__ rb,
    unsigned short* __restrict__ out, float* __restrict__ pool_out, int do_pool)
{
    int t0 = blockIdx.x * 256, o0 = blockIdx.y * 64, b = blockIdx.z;
    __shared__ __align__(16) unsigned short xs[264 * 40];
    __shared__ __align__(16) unsigned short wsh[4 * 64 * 40];
    __shared__ float pool_s[4][64];
    int tid = threadIdx.x;
    int wid = tid >> 6, lane = tid & 63;
    int n = lane & 15, g = lane >> 4;
    int wt = wid * 64;
    int d2 = 2 * d;
    int nrow = 256 + d2;
    const unsigned short* xb = x + (size_t)b * TP * Cin;

    int gg = tid & 3;
    int xr0 = tid >> 2;
    int tg0 = t0 - d2 + xr0;
    bool xv4 = xr0 < d2;
    const unsigned short* wbase = w4 + (size_t)(o0 + (tid >> 2)) * Cin + gg * 8;
    size_t wps = (size_t)256 * Cin;

    u16x8 sx0, sx1, sx2, sx3, sx4, sw0, sw1, sw2, sw3;
    const u16x8 zz = {0, 0, 0, 0, 0, 0, 0, 0};
#define LDST(C0)                                                               \
    do {                                                                       \
        sx0 = (tg0 >= 0) ? *(const u16x8*)&xb[(size_t)tg0 * Cin + (C0) + gg * 8] : zz; \
        sx1 = *(const u16x8*)&xb[(size_t)(tg0 + 64) * Cin + (C0) + gg * 8];    \
        sx2 = *(const u16x8*)&xb[(size_t)(tg0 + 128) * Cin + (C0) + gg * 8];   \
        sx3 = *(const u16x8*)&xb[(size_t)(tg0 + 192) * Cin + (C0) + gg * 8];   \
        sx4 = xv4 ? *(const u16x8*)&xb[(size_t)(tg0 + 256) * Cin + (C0) + gg * 8] : zz; \
        sw0 = *(const u16x8*)&wbase[(C0)];                                     \
        sw1 = *(const u16x8*)&wbase[wps + (C0)];                               \
        sw2 = *(const u16x8*)&wbase[2 * wps + (C0)];                           \
        sw3 = *(const u16x8*)&wbase[3 * wps + (C0)];                           \
    } while (0)

    f32x4 accc[4][4], accr[4][4];
#pragma unroll
    for (int i = 0; i < 4; ++i)
#pragma unroll
        for (int j = 0; j < 4; ++j) {
            accc[i][j] = (f32x4){0.f, 0.f, 0.f, 0.f};
            accr[i][j] = (f32x4){0.f, 0.f, 0.f, 0.f};
        }

    LDST(0);
    for (int c0 = 0; c0 < Cin; c0 += 32) {
        __syncthreads();
        *(u16x8*)&xs[xr0 * 40 + gg * 8] = sx0;
        *(u16x8*)&xs[(xr0 + 64) * 40 + gg * 8] = sx1;
        *(u16x8*)&xs[(xr0 + 128) * 40 + gg * 8] = sx2;
        *(u16x8*)&xs[(xr0 + 192) * 40 + gg * 8] = sx3;
        if (xv4) *(u16x8*)&xs[(xr0 + 256) * 40 + gg * 8] = sx4;
        {
            int wrow = (tid >> 2) * 40 + gg * 8;
            *(u16x8*)&wsh[wrow] = sw0;
            *(u16x8*)&wsh[2560 + wrow] = sw1;
            *(u16x8*)&wsh[5120 + wrow] = sw2;
            *(u16x8*)&wsh[7680 + wrow] = sw3;
        }
        __syncthreads();
        if (c0 + 32 < Cin) LDST(c0 + 32);

        s16x8 bfr[4][3];
#pragma unroll
        for (int j = 0; j < 4; ++j) {
            int tl = wt + j * 16 + n;
#pragma unroll
            for (int k = 0; k < 3; ++k)
                bfr[j][k] = *(const s16x8*)&xs[(tl + k * d) * 40 + g * 8];
        }
#pragma unroll
        for (int i = 0; i < 4; ++i) {
            int wrow = (i * 16 + n) * 40 + g * 8;
            s16x8 a0 = *(const s16x8*)&wsh[wrow];
            s16x8 a1 = *(const s16x8*)&wsh[2560 + wrow];
            s16x8 a2 = *(const s16x8*)&wsh[5120 + wrow];
            s16x8 ar = *(const s16x8*)&wsh[7680 + wrow];
#pragma unroll
            for (int j = 0; j < 4; ++j) {
                accc[i][j] = __builtin_amdgcn_mfma_f32_16x16x32_bf16(a0, bfr[j][0], accc[i][j], 0, 0, 0);
                accc[i][j] = __builtin_amdgcn_mfma_f32_16x16x32_bf16(a1, bfr[j][1], accc[i][j], 0, 0, 0);
                accc[i][j] = __builtin_amdgcn_mfma_f32_16x16x32_bf16(a2, bfr[j][2], accc[i][j], 0, 0, 0);
                accr[i][j] = __builtin_amdgcn_mfma_f32_16x16x32_bf16(ar, bfr[j][2], accr[i][j], 0, 0, 0);
            }
        }
    }
#undef LDST

#pragma unroll
    for (int i = 0; i < 4; ++i) {
        int ob = o0 + i * 16 + g * 4;
        float cbv0 = cb[ob], cbv1 = cb[ob + 1], cbv2 = cb[ob + 2], cbv3 = cb[ob + 3];
        float rbv0 = rb[ob], rbv1 = rb[ob + 1], rbv2 = rb[ob + 2], rbv3 = rb[ob + 3];
        float ps0 = 0.f, ps1 = 0.f, ps2 = 0.f, ps3 = 0.f;
#pragma unroll
        for (int j = 0; j < 4; ++j) {
            int t = t0 + wt + j * 16 + n;
            float v0 = fmaxf(accc[i][j][0] + cbv0, 0.f) + accr[i][j][0] + rbv0;
            float v1 = fmaxf(accc[i][j][1] + cbv1, 0.f) + accr[i][j][1] + rbv1;
            float v2 = fmaxf(accc[i][j][2] + cbv2, 0.f) + accr[i][j][2] + rbv2;
            float v3 = fmaxf(accc[i][j][3] + cbv3, 0.f) + accr[i][j][3] + rbv3;
            ps0 += v0; ps1 += v1; ps2 += v2; ps3 += v3;
            if (!do_pool) {
                u16x4 pk;
                pk[0] = f2bf(v0); pk[1] = f2bf(v1); pk[2] = f2bf(v2); pk[3] = f2bf(v3);
                *(u16x4*)&out[((size_t)b * TP + t) * HID + ob] = pk;
            }
        }
        if (do_pool) {
#pragma unroll
            for (int msk = 1; msk < 16; msk <<= 1) {
                ps0 += __shfl_xor(ps0, msk);
                ps1 += __shfl_xor(ps1, msk);
                ps2 += __shfl_xor(ps2, msk);
                ps3 += __shfl_xor(ps3, msk);
            }
            if (n == 0) {
                int ol = i * 16 + g * 4;
                pool_s[wid][ol + 0] = ps0;
                pool_s[wid][ol + 1] = ps1;
                pool_s[wid][ol + 2] = ps2;
                pool_s[wid][ol + 3] = ps3;
            }
        }
    }
    if (do_pool) {
        __syncthreads();
        if (tid < 64) {
            float s = pool_s[0][tid] + pool_s[1][tid] + pool_s[2][tid] + pool_s[3][tid];
            pool_out[((size_t)b * 4 + blockIdx.x) * HID + o0 + tid] = s;
        }
    }
}

// ---------------------------------------------------------------------------
// final: fc on pooled sums (4 t-slices) + MMD reduce.
// ---------------------------------------------------------------------------
__global__ __launch_bounds__(256) void final_kernel(
    const float* __restrict__ pp, const float* __restrict__ fcw,
    const float* __restrict__ fcb, const float* __restrict__ partials,
    float* __restrict__ dout)
{
    int tid = threadIdx.x;
    if (tid < 128) {
        int b = tid >> 2, k = tid & 3;
        float s = 0.f;
        for (int c = 0; c < HID; ++c) {
            float pc = 0.f;
#pragma unroll
            for (int xs = 0; xs < 4; ++xs) pc += pp[((size_t)b * 4 + xs) * HID + c];
            s += pc * fcw[k * HID + c];
        }
        dout[tid] = fcb[k] + s * (1.f / 1024.f);
    } else if (tid < 192) {
        int lane = tid - 128;
        float s = 0.f;
        for (int j = 0; j < 8; ++j) s += partials[lane + 64 * j];
        for (int off = 32; off; off >>= 1) s += __shfl_down(s, off);
        if (lane == 0) dout[128] = s * (1.f / (32.f * 32.f * 512.f));
    }
}

// ---------------------------------------------------------------------------
extern "C" void kernel_launch(void* const* d_in, const int* in_sizes, int n_in,
                              void* d_out, int out_size, void* d_ws, size_t ws_size,
                              hipStream_t stream)
{
    const float* feat1 = (const float*)d_in[0];
    const float* feat2 = (const float*)d_in[1];
    const float* wq_a = (const float*)d_in[2];
    const float* bq_a = (const float*)d_in[3];
    const float* wk_a = (const float*)d_in[4];
    const float* bk_a = (const float*)d_in[5];
    const float* wv_a = (const float*)d_in[6];
    const float* bv_a = (const float*)d_in[7];
    const float* wq_b = (const float*)d_in[8];
    const float* bq_b = (const float*)d_in[9];
    const float* wk_b = (const float*)d_in[10];
    const float* bk_b = (const float*)d_in[11];
    const float* wv_b = (const float*)d_in[12];
    const float* bv_b = (const float*)d_in[13];
    const float* cw0 = (const float*)d_in[14];
    const float* cb0 = (const float*)d_in[15];
    const float* rw0 = (const float*)d_in[16];
    const float* rb0 = (const float*)d_in[17];
    const float* cw1 = (const float*)d_in[18];
    const float* cb1 = (const float*)d_in[19];
    const float* rw1 = (const float*)d_in[20];
    const float* rb1 = (const float*)d_in[21];
    const float* cw2 = (const float*)d_in[22];
    const float* cb2 = (const float*)d_in[23];
    const float* rw2 = (const float*)d_in[24];
    const float* rb2 = (const float*)d_in[25];
    const float* fcw = (const float*)d_in[26];
    const float* fcb = (const float*)d_in[27];
    float* dout = (float*)d_out;

    // workspace layout (float offsets):
    //   Qbf @ 0 (1048576), Kbf @ 1048576, Vt @ 2097152
    //   f1tf @ 3145728 (fp32 2097152), f2tf @ 5242880
    //   xbuf @ 7340032 (bf16 [32][1024][128])
    //   wbuf @ 9437184 (tcn bf16 planes, 327680 floats)
    //   qkvw @ 9764864 (49152 floats)
    //   poolpart @ 9814016 (32*4*256 = 32768 floats)
    //   mmdpart @ 9846784 (512)
    //   h_a aliases 0..4194304 ; h_b aliases 4194304..8388608
    float* ws = (float*)d_ws;
    unsigned short* Qbf = (unsigned short*)ws;
    unsigned short* Kbf = (unsigned short*)(ws + 1048576);
    unsigned short* Vt  = (unsigned short*)(ws + 2097152);
    float* f1tf = ws + 3145728;
    float* f2tf = ws + 5242880;
    unsigned short* xbuf = (unsigned short*)(ws + 7340032);
    unsigned short* wbuf = (unsigned short*)(ws + 9437184);
    unsigned short* wb0 = wbuf;
    unsigned short* wb1 = wbuf + 131072;
    unsigned short* wb2 = wbuf + 393216;
    unsigned short* qkvw = (unsigned short*)(ws + 9764864);
    unsigned short* w3a = qkvw;
    unsigned short* w3b = qkvw + 3 * 16384;
    float* poolpart = ws + 9814016;
    float* mmdpart  = ws + 9846784;
    unsigned short* h_a = (unsigned short*)ws;
    unsigned short* h_b = (unsigned short*)(ws + 4194304);

    // weight prep
    prep_all_kernel<<<dim3(2944), 256, 0, stream>>>(
        wq_a, wk_a, wv_a, wq_b, wk_b, wv_b,
        cw0, rw0, cw1, rw1, cw2, rw2, qkvw, wb0, wb1, wb2);

    // branch A: Q from feat2 (fp32 c-major), K/V from feat1 (fp32 c-major)
    proj_mfma_kernel<<<dim3(16, 32), 256, 0, stream>>>(
        feat2, 0, 65536LL, feat1, 0, 65536LL, w3a,
        bq_a, bk_a, bv_a, Qbf, Kbf, Vt);
    attn_mfma_kernel<<<dim3(8, 32), 256, 0, stream>>>(
        Qbf, Kbf, Vt, feat1, 65536LL, 512, 1, f1tf, xbuf, 0);

    // branch B: Q from updated f1 (xbuf rows 0..511, bf16 t-major), K/V from feat2
    proj_mfma_kernel<<<dim3(16, 32), 256, 0, stream>>>(
        xbuf, 1, (long long)TP * FF, feat2, 0, 65536LL, w3b,
        bq_b, bk_b, bv_b, Qbf, Kbf, Vt);
    attn_mfma_kernel<<<dim3(8, 32), 256, 0, stream>>>(
        Qbf, Kbf, Vt, feat2, 65536LL, 512, 1, f2tf, xbuf, 512);

    // MMD partials (before TCN overwrites f1tf/f2tf regions)
    mmd_kernel<<<dim3(512), 256, 0, stream>>>(f1tf, f2tf, mmdpart);

    // TCN stack: xbuf(128ch) -> h_a -> h_b -> pooled (fused)
    tcn_mfma_kernel<<<dim3(4, 4, 32), 256, 0, stream>>>(xbuf, 128, 1, wb0, cb0, rb0, h_a, nullptr, 0);
    tcn_mfma_kernel<<<dim3(4, 4, 32), 256, 0, stream>>>(h_a, 256, 2, wb1, cb1, rb1, h_b, nullptr, 0);
    tcn_mfma_kernel<<<dim3(4, 4, 32), 256, 0, stream>>>(h_b, 256, 4, wb2, cb2, rb2, h_a, poolpart, 1);

    final_kernel<<<dim3(1), 256, 0, stream>>>(poolpart, fcw, fcb, mmdpart, dout);
}

// Round 9
// 180.340 us; speedup vs baseline: 1.8576x; 1.0133x over previous
//
#include <hip/hip_runtime.h>

#define BB 32
#define TT 512
#define FF 128
#define HID 256
#define TP 1024

typedef __attribute__((ext_vector_type(8))) short s16x8;
typedef __attribute__((ext_vector_type(8))) unsigned short u16x8;
typedef __attribute__((ext_vector_type(4))) unsigned short u16x4;
typedef __attribute__((ext_vector_type(4))) float f32x4;

static __device__ __forceinline__ unsigned short f2bf(float f) {
    unsigned u = __builtin_bit_cast(unsigned, f);
    u = (u + 0x7FFFu + ((u >> 16) & 1u)) >> 16;
    return (unsigned short)u;
}
static __device__ __forceinline__ float bf2f(unsigned short b) {
    return __builtin_bit_cast(float, ((unsigned)b) << 16);
}

// ---------------------------------------------------------------------------
// All weight prep in one launch.
//   [0, 98304):        qkvw bf16 [6][128][128], planes 0,3 pre-scaled
//   [98304, 229376):   tcn w0 (Cin=128)
//   [229376, 491520):  tcn w1 (Cin=256)
//   [491520, 753664):  tcn w2 (Cin=256)
// ---------------------------------------------------------------------------
static __device__ __forceinline__ void tcnw_prep(
    int idx, const float* __restrict__ cw, const float* __restrict__ rw,
    unsigned short* __restrict__ out, int Cin)
{
    int p = idx / (256 * Cin);
    int rem = idx - p * 256 * Cin;
    int o = rem / Cin, c = rem - o * Cin;
    float v = (p < 3) ? cw[(o * Cin + c) * 3 + p] : rw[o * Cin + c];
    out[idx] = f2bf(v);
}

__global__ __launch_bounds__(256) void prep_all_kernel(
    const float* __restrict__ wqa, const float* __restrict__ wka,
    const float* __restrict__ wva, const float* __restrict__ wqb,
    const float* __restrict__ wkb, const float* __restrict__ wvb,
    const float* __restrict__ cw0, const float* __restrict__ rw0,
    const float* __restrict__ cw1, const float* __restrict__ rw1,
    const float* __restrict__ cw2, const float* __restrict__ rw2,
    unsigned short* __restrict__ qkvw, unsigned short* __restrict__ wb0,
    unsigned short* __restrict__ wb1, unsigned short* __restrict__ wb2)
{
    int idx = blockIdx.x * 256 + threadIdx.x;
    if (idx < 98304) {
        int p = idx >> 14, rc = idx & 16383;
        const float* srcs[6] = {wqa, wka, wva, wqb, wkb, wvb};
        float v = srcs[p][rc];
        if (p == 0 || p == 3) v *= 0.088388347648318447f;
        qkvw[idx] = f2bf(v);
    } else if (idx < 229376) {
        tcnw_prep(idx - 98304, cw0, rw0, wb0, 128);
    } else if (idx < 491520) {
        tcnw_prep(idx - 229376, cw1, rw1, wb1, 256);
    } else if (idx < 753664) {
        tcnw_prep(idx - 491520, cw2, rw2, wb2, 256);
    }
}

// ---------------------------------------------------------------------------
// QKV projection via MFMA.  x sources staged to LDS with mode:
//   mode 0: fp32 [b][128][512] (c-major), batch stride in floats
//   mode 1: bf16 [b][t][128]   (t-major), batch stride in u16
// grid (16, 32), block 256 = 4 waves.
// ---------------------------------------------------------------------------
__global__ __launch_bounds__(256) void proj_mfma_kernel(
    const void* __restrict__ xq_src, int xq_mode, long long xq_bs,
    const void* __restrict__ xkv_src, int xkv_mode, long long xkv_bs,
    const unsigned short* __restrict__ w3,
    const float* __restrict__ bq, const float* __restrict__ bk,
    const float* __restrict__ bv,
    unsigned short* __restrict__ Qo, unsigned short* __restrict__ Ko,
    unsigned short* __restrict__ Vt)
{
    int t0 = blockIdx.x * 32, b = blockIdx.y;
    __shared__ __align__(16) unsigned short xsq[32 * 136];
    __shared__ __align__(16) unsigned short xskv[32 * 136];
    int tid = threadIdx.x;
    int wid = tid >> 6, lane = tid & 63;
    int n = lane & 15, g = lane >> 4;
    int tsub = (wid & 1) * 16, fh = (wid >> 1) * 64;

    if (xq_mode == 0) {
        const float* s = (const float*)xq_src + (size_t)b * xq_bs;
        for (int l = tid; l < 4096; l += 256) {
            int c = l >> 5, tt = l & 31;
            xsq[tt * 136 + c] = f2bf(s[(size_t)c * TT + t0 + tt]);
        }
    } else {
        const unsigned short* s = (const unsigned short*)xq_src + (size_t)b * xq_bs;
        for (int l = tid; l < 512; l += 256) {
            int r = l >> 4, cc = l & 15;
            *(u16x8*)&xsq[r * 136 + cc * 8] = *(const u16x8*)&s[(size_t)(t0 + r) * FF + cc * 8];
        }
    }
    if (xkv_mode == 0) {
        const float* s = (const float*)xkv_src + (size_t)b * xkv_bs;
        for (int l = tid; l < 4096; l += 256) {
            int c = l >> 5, tt = l & 31;
            xskv[tt * 136 + c] = f2bf(s[(size_t)c * TT + t0 + tt]);
        }
    } else {
        const unsigned short* s = (const unsigned short*)xkv_src + (size_t)b * xkv_bs;
        for (int l = tid; l < 512; l += 256) {
            int r = l >> 4, cc = l & 15;
            *(u16x8*)&xskv[r * 136 + cc * 8] = *(const u16x8*)&s[(size_t)(t0 + r) * FF + cc * 8];
        }
    }
    __syncthreads();

    f32x4 acc[3][4];
#pragma unroll
    for (int p = 0; p < 3; ++p)
#pragma unroll
        for (int i = 0; i < 4; ++i) acc[p][i] = (f32x4){0.f, 0.f, 0.f, 0.f};

#pragma unroll
    for (int kk = 0; kk < 4; ++kk) {
        s16x8 bxq = *(const s16x8*)&xsq[(tsub + n) * 136 + kk * 32 + g * 8];
        s16x8 bxkv = *(const s16x8*)&xskv[(tsub + n) * 136 + kk * 32 + g * 8];
#pragma unroll
        for (int i = 0; i < 4; ++i) {
            const unsigned short* wb = &w3[(size_t)(fh + i * 16 + n) * 128 + kk * 32 + g * 8];
            s16x8 a0 = *(const s16x8*)&wb[0];
            s16x8 a1 = *(const s16x8*)&wb[16384];
            s16x8 a2 = *(const s16x8*)&wb[32768];
            acc[0][i] = __builtin_amdgcn_mfma_f32_16x16x32_bf16(a0, bxq, acc[0][i], 0, 0, 0);
            acc[1][i] = __builtin_amdgcn_mfma_f32_16x16x32_bf16(a1, bxkv, acc[1][i], 0, 0, 0);
            acc[2][i] = __builtin_amdgcn_mfma_f32_16x16x32_bf16(a2, bxkv, acc[2][i], 0, 0, 0);
        }
    }

    const float scale = 0.088388347648318447f;
    int t = t0 + tsub + n;
#pragma unroll
    for (int i = 0; i < 4; ++i) {
        int fb = fh + i * 16 + g * 4;
        u16x4 pk;
#pragma unroll
        for (int r = 0; r < 4; ++r) pk[r] = f2bf(acc[0][i][r] + bq[fb + r] * scale);
        *(u16x4*)&Qo[((size_t)b * TT + t) * FF + fb] = pk;
#pragma unroll
        for (int r = 0; r < 4; ++r) pk[r] = f2bf(acc[1][i][r] + bk[fb + r]);
        *(u16x4*)&Ko[((size_t)b * TT + t) * FF + fb] = pk;
#pragma unroll
        for (int r = 0; r < 4; ++r)
            Vt[((size_t)b * FF + fb + r) * TT + t] = f2bf(acc[2][i][r] + bv[fb + r]);
    }
}

// ---------------------------------------------------------------------------
// Flash attention via MFMA.  grid (8, 32), block 256 = 4 waves.
// ---------------------------------------------------------------------------
__global__ __launch_bounds__(256) void attn_mfma_kernel(
    const unsigned short* __restrict__ Qb, const unsigned short* __restrict__ Kb,
    const unsigned short* __restrict__ Vtb,
    const float* __restrict__ orig, long long bso, int cso, int tso,
    float* __restrict__ out_tf, unsigned short* __restrict__ out_x, int xoff)
{
    __shared__ __align__(16) unsigned short Ks[64 * 136];
    __shared__ __align__(16) unsigned short Vs[128 * 72];
    __shared__ __align__(16) unsigned short Ps[4 * 16 * 68];

    int t0 = blockIdx.x * 64, b = blockIdx.y;
    int tid = threadIdx.x;
    int wid = tid >> 6, lane = tid & 63;
    int n = lane & 15, g = lane >> 4;
    int q0 = t0 + wid * 16;
    unsigned short* Pw = &Ps[wid * 1088];

    s16x8 qf[4];
#pragma unroll
    for (int kk = 0; kk < 4; ++kk)
        qf[kk] = *(const s16x8*)&Qb[((size_t)b * TT + q0 + n) * FF + kk * 32 + g * 8];

    u16x8 kst[4], vst[4];
#pragma unroll
    for (int ii = 0; ii < 4; ++ii) {
        int l = tid + 256 * ii;
        kst[ii] = *(const u16x8*)&Kb[((size_t)b * TT + (l >> 4)) * FF + (l & 15) * 8];
        vst[ii] = *(const u16x8*)&Vtb[((size_t)b * FF + (l >> 3)) * TT + (l & 7) * 8];
    }

    f32x4 O[8];
#pragma unroll
    for (int ft = 0; ft < 8; ++ft) O[ft] = (f32x4){0.f, 0.f, 0.f, 0.f};
    float m[4] = {-1e30f, -1e30f, -1e30f, -1e30f};
    float lsum[4] = {0.f, 0.f, 0.f, 0.f};

    for (int it = 0; it < 8; ++it) {
        __syncthreads();
#pragma unroll
        for (int ii = 0; ii < 4; ++ii) {
            int l = tid + 256 * ii;
            *(u16x8*)&Ks[(l >> 4) * 136 + (l & 15) * 8] = kst[ii];
            *(u16x8*)&Vs[(l >> 3) * 72 + (l & 7) * 8] = vst[ii];
        }
        __syncthreads();
        if (it < 7) {
            int s0n = (it + 1) * 64;
#pragma unroll
            for (int ii = 0; ii < 4; ++ii) {
                int l = tid + 256 * ii;
                kst[ii] = *(const u16x8*)&Kb[((size_t)b * TT + s0n + (l >> 4)) * FF + (l & 15) * 8];
                vst[ii] = *(const u16x8*)&Vtb[((size_t)b * FF + (l >> 3)) * TT + s0n + (l & 7) * 8];
            }
        }

        f32x4 acc[4];
#pragma unroll
        for (int st = 0; st < 4; ++st) acc[st] = (f32x4){0.f, 0.f, 0.f, 0.f};
        __builtin_amdgcn_s_setprio(1);
#pragma unroll
        for (int kk = 0; kk < 4; ++kk) {
#pragma unroll
            for (int st = 0; st < 4; ++st) {
                s16x8 kf = *(const s16x8*)&Ks[(st * 16 + n) * 136 + kk * 32 + g * 8];
                acc[st] = __builtin_amdgcn_mfma_f32_16x16x32_bf16(qf[kk], kf, acc[st], 0, 0, 0);
            }
        }
        __builtin_amdgcn_s_setprio(0);

        float mnew[4], c[4], rs[4];
#pragma unroll
        for (int r = 0; r < 4; ++r) {
            float tm = fmaxf(fmaxf(acc[0][r], acc[1][r]), fmaxf(acc[2][r], acc[3][r]));
#pragma unroll
            for (int msk = 1; msk < 16; msk <<= 1) tm = fmaxf(tm, __shfl_xor(tm, msk));
            mnew[r] = fmaxf(m[r], tm);
            c[r] = __expf(m[r] - mnew[r]);
            m[r] = mnew[r];
            rs[r] = 0.f;
        }
#pragma unroll
        for (int st = 0; st < 4; ++st) {
#pragma unroll
            for (int r = 0; r < 4; ++r) {
                float p = __expf(acc[st][r] - mnew[r]);
                rs[r] += p;
                Pw[(g * 4 + r) * 68 + st * 16 + n] = f2bf(p);
            }
        }
#pragma unroll
        for (int r = 0; r < 4; ++r) {
#pragma unroll
            for (int msk = 1; msk < 16; msk <<= 1) rs[r] += __shfl_xor(rs[r], msk);
            lsum[r] = lsum[r] * c[r] + rs[r];
        }
#pragma unroll
        for (int ft = 0; ft < 8; ++ft) {
#pragma unroll
            for (int r = 0; r < 4; ++r) O[ft][r] *= c[r];
        }

        __builtin_amdgcn_s_setprio(1);
#pragma unroll
        for (int ks = 0; ks < 2; ++ks) {
            s16x8 pf = *(const s16x8*)&Pw[n * 68 + ks * 32 + g * 8];
#pragma unroll
            for (int ft = 0; ft < 8; ++ft) {
                s16x8 vf = *(const s16x8*)&Vs[(ft * 16 + n) * 72 + ks * 32 + g * 8];
                O[ft] = __builtin_amdgcn_mfma_f32_16x16x32_bf16(pf, vf, O[ft], 0, 0, 0);
            }
        }
        __builtin_amdgcn_s_setprio(0);
    }

    float rinv[4];
#pragma unroll
    for (int r = 0; r < 4; ++r) rinv[r] = 1.f / lsum[r];
#pragma unroll
    for (int ft = 0; ft < 8; ++ft) {
        int f = ft * 16 + n;
#pragma unroll
        for (int r = 0; r < 4; ++r) {
            int q = q0 + g * 4 + r;
            float val = O[ft][r] * rinv[r];
            float xv = orig[bso * b + (size_t)f * cso + (size_t)q * tso];
            float res = val * xv + xv;
            out_tf[((size_t)b * TT + q) * FF + f] = res;
            out_x[((size_t)b * TP + xoff + q) * FF + f] = f2bf(res);
        }
    }
}

// ---------------------------------------------------------------------------
// MMD partials per timepoint via split-precision MFMA Gram matrices.
// ---------------------------------------------------------------------------
__global__ __launch_bounds__(256) void mmd_kernel(
    const float* __restrict__ f1, const float* __restrict__ f2,
    float* __restrict__ partials)
{
    int t = blockIdx.x;
    __shared__ __align__(16) unsigned short X1h[32 * 136], X1l[32 * 136];
    __shared__ __align__(16) unsigned short X2h[32 * 136], X2l[32 * 136];
    __shared__ float Gs[3][32][33];
    __shared__ float red[256];
    int tid = threadIdx.x;

    for (int l = tid; l < 4096; l += 256) {
        int i = l >> 7, f = l & 127;
        float v1 = f1[((size_t)i * TT + t) * FF + f];
        float v2 = f2[((size_t)i * TT + t) * FF + f];
        unsigned short h1 = f2bf(v1);
        unsigned short h2 = f2bf(v2);
        X1h[i * 136 + f] = h1;
        X1l[i * 136 + f] = f2bf(v1 - bf2f(h1));
        X2h[i * 136 + f] = h2;
        X2l[i * 136 + f] = f2bf(v2 - bf2f(h2));
    }
    __syncthreads();

    int wid = tid >> 6, lane = tid & 63;
    int n = lane & 15, g = lane >> 4;
#pragma unroll
    for (int uu = 0; uu < 3; ++uu) {
        int u = wid * 3 + uu;
        int gram = u >> 2, quad = u & 3;
        int qi = quad >> 1, qj = quad & 1;
        const unsigned short* Ah = (gram == 1) ? X2h : X1h;
        const unsigned short* Al = (gram == 1) ? X2l : X1l;
        const unsigned short* Bh = (gram == 0) ? X1h : X2h;
        const unsigned short* Bl = (gram == 0) ? X1l : X2l;
        f32x4 acc = (f32x4){0.f, 0.f, 0.f, 0.f};
#pragma unroll
        for (int kk = 0; kk < 4; ++kk) {
            int ao = (qi * 16 + n) * 136 + kk * 32 + g * 8;
            int bo = (qj * 16 + n) * 136 + kk * 32 + g * 8;
            s16x8 ah = *(const s16x8*)&Ah[ao];
            s16x8 al = *(const s16x8*)&Al[ao];
            s16x8 bh = *(const s16x8*)&Bh[bo];
            s16x8 bl = *(const s16x8*)&Bl[bo];
            acc = __builtin_amdgcn_mfma_f32_16x16x32_bf16(ah, bh, acc, 0, 0, 0);
            acc = __builtin_amdgcn_mfma_f32_16x16x32_bf16(ah, bl, acc, 0, 0, 0);
            acc = __builtin_amdgcn_mfma_f32_16x16x32_bf16(al, bh, acc, 0, 0, 0);
        }
#pragma unroll
        for (int r = 0; r < 4; ++r)
            Gs[gram][qi * 16 + g * 4 + r][qj * 16 + n] = acc[r];
    }
    __syncthreads();

    float s = 0.f;
#pragma unroll
    for (int r = 0; r < 4; ++r) {
        int p = tid + 256 * r;
        int i = p >> 5, j = p & 31;
        float d11 = Gs[0][i][i] + Gs[0][j][j] - 2.f * Gs[0][i][j];
        float d22 = Gs[1][i][i] + Gs[1][j][j] - 2.f * Gs[1][i][j];
        float d12 = Gs[0][i][i] + Gs[1][j][j] - 2.f * Gs[2][i][j];
        s += __expf(-0.5f * d11) + __expf(-0.5f * d22) - 2.f * __expf(-0.5f * d12);
    }
    red[tid] = s;
    __syncthreads();
    for (int off = 128; off; off >>= 1) {
        if (tid < off) red[tid] += red[tid + off];
        __syncthreads();
    }
    if (tid == 0) partials[t] = red[0];
}

// ---------------------------------------------------------------------------
// TCN layer via MFMA, 64o x 64t wave tile, weights + x staged in LDS,
// load-early/write-late; coalesced output staging via LDS reuse.
// grid (4, 4, 32), block 256 = 4 waves.
// ---------------------------------------------------------------------------
__global__ __launch_bounds__(256, 2) void tcn_mfma_kernel(
    const unsigned short* __restrict__ x, int Cin, int d,
    const unsigned short* __restrict__ w4,
    const float* __restrict__ cb, const float* __restrict__ rb,
    unsigned short* __restrict__ out, float* __restrict__ pool_out, int do_pool)
{
    int t0 = blockIdx.x * 256, o0 = blockIdx.y * 64, b = blockIdx.z;
    // union: K-loop uses xs (264*40=10560) + wsh (4*64*40=10240) = 20800 u16;
    // epilogue reuses the same memory as ot[256][66] = 16896 u16.
    __shared__ __align__(16) unsigned short smem[20800];
    __shared__ float pool_s[4][64];
    unsigned short* xs = smem;
    unsigned short* wsh = smem + 10560;
    int tid = threadIdx.x;
    int wid = tid >> 6, lane = tid & 63;
    int n = lane & 15, g = lane >> 4;
    int wt = wid * 64;
    int d2 = 2 * d;
    const unsigned short* xb = x + (size_t)b * TP * Cin;

    int gg = tid & 3;
    int xr0 = tid >> 2;
    int tg0 = t0 - d2 + xr0;
    bool xv4 = xr0 < d2;
    const unsigned short* wbase = w4 + (size_t)(o0 + (tid >> 2)) * Cin + gg * 8;
    size_t wps = (size_t)256 * Cin;

    u16x8 sx0, sx1, sx2, sx3, sx4, sw0, sw1, sw2, sw3;
    const u16x8 zz = {0, 0, 0, 0, 0, 0, 0, 0};
#define LDST(C0)                                                               \
    do {                                                                       \
        sx0 = (tg0 >= 0) ? *(const u16x8*)&xb[(size_t)tg0 * Cin + (C0) + gg * 8] : zz; \
        sx1 = *(const u16x8*)&xb[(size_t)(tg0 + 64) * Cin + (C0) + gg * 8];    \
        sx2 = *(const u16x8*)&xb[(size_t)(tg0 + 128) * Cin + (C0) + gg * 8];   \
        sx3 = *(const u16x8*)&xb[(size_t)(tg0 + 192) * Cin + (C0) + gg * 8];   \
        sx4 = xv4 ? *(const u16x8*)&xb[(size_t)(tg0 + 256) * Cin + (C0) + gg * 8] : zz; \
        sw0 = *(const u16x8*)&wbase[(C0)];                                     \
        sw1 = *(const u16x8*)&wbase[wps + (C0)];                               \
        sw2 = *(const u16x8*)&wbase[2 * wps + (C0)];                           \
        sw3 = *(const u16x8*)&wbase[3 * wps + (C0)];                           \
    } while (0)

    f32x4 accc[4][4], accr[4][4];
#pragma unroll
    for (int i = 0; i < 4; ++i)
#pragma unroll
        for (int j = 0; j < 4; ++j) {
            accc[i][j] = (f32x4){0.f, 0.f, 0.f, 0.f};
            accr[i][j] = (f32x4){0.f, 0.f, 0.f, 0.f};
        }

    LDST(0);
    for (int c0 = 0; c0 < Cin; c0 += 32) {
        __syncthreads();
        *(u16x8*)&xs[xr0 * 40 + gg * 8] = sx0;
        *(u16x8*)&xs[(xr0 + 64) * 40 + gg * 8] = sx1;
        *(u16x8*)&xs[(xr0 + 128) * 40 + gg * 8] = sx2;
        *(u16x8*)&xs[(xr0 + 192) * 40 + gg * 8] = sx3;
        if (xv4) *(u16x8*)&xs[(xr0 + 256) * 40 + gg * 8] = sx4;
        {
            int wrow = (tid >> 2) * 40 + gg * 8;
            *(u16x8*)&wsh[wrow] = sw0;
            *(u16x8*)&wsh[2560 + wrow] = sw1;
            *(u16x8*)&wsh[5120 + wrow] = sw2;
            *(u16x8*)&wsh[7680 + wrow] = sw3;
        }
        __syncthreads();
        if (c0 + 32 < Cin) LDST(c0 + 32);

        s16x8 bfr[4][3];
#pragma unroll
        for (int j = 0; j < 4; ++j) {
            int tl = wt + j * 16 + n;
#pragma unroll
            for (int k = 0; k < 3; ++k)
                bfr[j][k] = *(const s16x8*)&xs[(tl + k * d) * 40 + g * 8];
        }
        __builtin_amdgcn_s_setprio(1);
#pragma unroll
        for (int i = 0; i < 4; ++i) {
            int wrow = (i * 16 + n) * 40 + g * 8;
            s16x8 a0 = *(const s16x8*)&wsh[wrow];
            s16x8 a1 = *(const s16x8*)&wsh[2560 + wrow];
            s16x8 a2 = *(const s16x8*)&wsh[5120 + wrow];
            s16x8 ar = *(const s16x8*)&wsh[7680 + wrow];
#pragma unroll
            for (int j = 0; j < 4; ++j) {
                accc[i][j] = __builtin_amdgcn_mfma_f32_16x16x32_bf16(a0, bfr[j][0], accc[i][j], 0, 0, 0);
                accc[i][j] = __builtin_amdgcn_mfma_f32_16x16x32_bf16(a1, bfr[j][1], accc[i][j], 0, 0, 0);
                accc[i][j] = __builtin_amdgcn_mfma_f32_16x16x32_bf16(a2, bfr[j][2], accc[i][j], 0, 0, 0);
                accr[i][j] = __builtin_amdgcn_mfma_f32_16x16x32_bf16(ar, bfr[j][2], accr[i][j], 0, 0, 0);
            }
        }
        __builtin_amdgcn_s_setprio(0);
    }
#undef LDST

    if (!do_pool) {
        // coalesced epilogue: fragments -> ot[256][66] in LDS -> 128B row stores
        __syncthreads();   // all K-loop LDS reads complete before reuse
        unsigned short* ot = smem;
#pragma unroll
        for (int i = 0; i < 4; ++i) {
            int ob = o0 + i * 16 + g * 4;
            float cbv0 = cb[ob], cbv1 = cb[ob + 1], cbv2 = cb[ob + 2], cbv3 = cb[ob + 3];
            float rbv0 = rb[ob], rbv1 = rb[ob + 1], rbv2 = rb[ob + 2], rbv3 = rb[ob + 3];
#pragma unroll
            for (int j = 0; j < 4; ++j) {
                int tl = wt + j * 16 + n;
                u16x4 pk;
                pk[0] = f2bf(fmaxf(accc[i][j][0] + cbv0, 0.f) + accr[i][j][0] + rbv0);
                pk[1] = f2bf(fmaxf(accc[i][j][1] + cbv1, 0.f) + accr[i][j][1] + rbv1);
                pk[2] = f2bf(fmaxf(accc[i][j][2] + cbv2, 0.f) + accr[i][j][2] + rbv2);
                pk[3] = f2bf(fmaxf(accc[i][j][3] + cbv3, 0.f) + accr[i][j][3] + rbv3);
                *(u16x4*)&ot[tl * 66 + i * 16 + g * 4] = pk;
            }
        }
        __syncthreads();
        int tl = tid >> 3, c8 = tid & 7;
#pragma unroll
        for (int s = 0; s < 8; ++s) {
            int trow = tl + 32 * s;
            *(u16x8*)&out[((size_t)b * TP + t0 + trow) * HID + o0 + c8 * 8] =
                *(const u16x8*)&ot[trow * 66 + c8 * 8];
        }
    } else {
        // pooled epilogue (layer 3): reduce sum over t, no h write
#pragma unroll
        for (int i = 0; i < 4; ++i) {
            int ob = o0 + i * 16 + g * 4;
            float cbv0 = cb[ob], cbv1 = cb[ob + 1], cbv2 = cb[ob + 2], cbv3 = cb[ob + 3];
            float rbv0 = rb[ob], rbv1 = rb[ob + 1], rbv2 = rb[ob + 2], rbv3 = rb[ob + 3];
            float ps0 = 0.f, ps1 = 0.f, ps2 = 0.f, ps3 = 0.f;
#pragma unroll
            for (int j = 0; j < 4; ++j) {
                ps0 += fmaxf(accc[i][j][0] + cbv0, 0.f) + accr[i][j][0] + rbv0;
                ps1 += fmaxf(accc[i][j][1] + cbv1, 0.f) + accr[i][j][1] + rbv1;
                ps2 += fmaxf(accc[i][j][2] + cbv2, 0.f) + accr[i][j][2] + rbv2;
                ps3 += fmaxf(accc[i][j][3] + cbv3, 0.f) + accr[i][j][3] + rbv3;
            }
#pragma unroll
            for (int msk = 1; msk < 16; msk <<= 1) {
                ps0 += __shfl_xor(ps0, msk);
                ps1 += __shfl_xor(ps1, msk);
                ps2 += __shfl_xor(ps2, msk);
                ps3 += __shfl_xor(ps3, msk);
            }
            if (n == 0) {
                int ol = i * 16 + g * 4;
                pool_s[wid][ol + 0] = ps0;
                pool_s[wid][ol + 1] = ps1;
                pool_s[wid][ol + 2] = ps2;
                pool_s[wid][ol + 3] = ps3;
            }
        }
        __syncthreads();
        if (tid < 64) {
            float s = pool_s[0][tid] + pool_s[1][tid] + pool_s[2][tid] + pool_s[3][tid];
            pool_out[((size_t)b * 4 + blockIdx.x) * HID + o0 + tid] = s;
        }
    }
}

// ---------------------------------------------------------------------------
// final: fc on pooled sums (4 t-slices) + MMD reduce.
// ---------------------------------------------------------------------------
__global__ __launch_bounds__(256) void final_kernel(
    const float* __restrict__ pp, const float* __restrict__ fcw,
    const float* __restrict__ fcb, const float* __restrict__ partials,
    float* __restrict__ dout)
{
    int tid = threadIdx.x;
    if (tid < 128) {
        int b = tid >> 2, k = tid & 3;
        float s = 0.f;
        for (int c = 0; c < HID; ++c) {
            float pc = 0.f;
#pragma unroll
            for (int xs = 0; xs < 4; ++xs) pc += pp[((size_t)b * 4 + xs) * HID + c];
            s += pc * fcw[k * HID + c];
        }
        dout[tid] = fcb[k] + s * (1.f / 1024.f);
    } else if (tid < 192) {
        int lane = tid - 128;
        float s = 0.f;
        for (int j = 0; j < 8; ++j) s += partials[lane + 64 * j];
        for (int off = 32; off; off >>= 1) s += __shfl_down(s, off);
        if (lane == 0) dout[128] = s * (1.f / (32.f * 32.f * 512.f));
    }
}

// ---------------------------------------------------------------------------
extern "C" void kernel_launch(void* const* d_in, const int* in_sizes, int n_in,
                              void* d_out, int out_size, void* d_ws, size_t ws_size,
                              hipStream_t stream)
{
    const float* feat1 = (const float*)d_in[0];
    const float* feat2 = (const float*)d_in[1];
    const float* wq_a = (const float*)d_in[2];
    const float* bq_a = (const float*)d_in[3];
    const float* wk_a = (const float*)d_in[4];
    const float* bk_a = (const float*)d_in[5];
    const float* wv_a = (const float*)d_in[6];
    const float* bv_a = (const float*)d_in[7];
    const float* wq_b = (const float*)d_in[8];
    const float* bq_b = (const float*)d_in[9];
    const float* wk_b = (const float*)d_in[10];
    const float* bk_b = (const float*)d_in[11];
    const float* wv_b = (const float*)d_in[12];
    const float* bv_b = (const float*)d_in[13];
    const float* cw0 = (const float*)d_in[14];
    const float* cb0 = (const float*)d_in[15];
    const float* rw0 = (const float*)d_in[16];
    const float* rb0 = (const float*)d_in[17];
    const float* cw1 = (const float*)d_in[18];
    const float* cb1 = (const float*)d_in[19];
    const float* rw1 = (const float*)d_in[20];
    const float* rb1 = (const float*)d_in[21];
    const float* cw2 = (const float*)d_in[22];
    const float* cb2 = (const float*)d_in[23];
    const float* rw2 = (const float*)d_in[24];
    const float* rb2 = (const float*)d_in[25];
    const float* fcw = (const float*)d_in[26];
    const float* fcb = (const float*)d_in[27];
    float* dout = (float*)d_out;

    float* ws = (float*)d_ws;
    unsigned short* Qbf = (unsigned short*)ws;
    unsigned short* Kbf = (unsigned short*)(ws + 1048576);
    unsigned short* Vt  = (unsigned short*)(ws + 2097152);
    float* f1tf = ws + 3145728;
    float* f2tf = ws + 5242880;
    unsigned short* xbuf = (unsigned short*)(ws + 7340032);
    unsigned short* wbuf = (unsigned short*)(ws + 9437184);
    unsigned short* wb0 = wbuf;
    unsigned short* wb1 = wbuf + 131072;
    unsigned short* wb2 = wbuf + 393216;
    unsigned short* qkvw = (unsigned short*)(ws + 9764864);
    unsigned short* w3a = qkvw;
    unsigned short* w3b = qkvw + 3 * 16384;
    float* poolpart = ws + 9814016;
    float* mmdpart  = ws + 9846784;
    unsigned short* h_a = (unsigned short*)ws;
    unsigned short* h_b = (unsigned short*)(ws + 4194304);

    prep_all_kernel<<<dim3(2944), 256, 0, stream>>>(
        wq_a, wk_a, wv_a, wq_b, wk_b, wv_b,
        cw0, rw0, cw1, rw1, cw2, rw2, qkvw, wb0, wb1, wb2);

    proj_mfma_kernel<<<dim3(16, 32), 256, 0, stream>>>(
        feat2, 0, 65536LL, feat1, 0, 65536LL, w3a,
        bq_a, bk_a, bv_a, Qbf, Kbf, Vt);
    attn_mfma_kernel<<<dim3(8, 32), 256, 0, stream>>>(
        Qbf, Kbf, Vt, feat1, 65536LL, 512, 1, f1tf, xbuf, 0);

    proj_mfma_kernel<<<dim3(16, 32), 256, 0, stream>>>(
        xbuf, 1, (long long)TP * FF, feat2, 0, 65536LL, w3b,
        bq_b, bk_b, bv_b, Qbf, Kbf, Vt);
    attn_mfma_kernel<<<dim3(8, 32), 256, 0, stream>>>(
        Qbf, Kbf, Vt, feat2, 65536LL, 512, 1, f2tf, xbuf, 512);

    mmd_kernel<<<dim3(512), 256, 0, stream>>>(f1tf, f2tf, mmdpart);

    tcn_mfma_kernel<<<dim3(4, 4, 32), 256, 0, stream>>>(xbuf, 128, 1, wb0, cb0, rb0, h_a, nullptr, 0);
    tcn_mfma_kernel<<<dim3(4, 4, 32), 256, 0, stream>>>(h_a, 256, 2, wb1, cb1, rb1, h_b, nullptr, 0);
    tcn_mfma_kernel<<<dim3(4, 4, 32), 256, 0, stream>>>(h_b, 256, 4, wb2, cb2, rb2, h_a, poolpart, 1);

    final_kernel<<<dim3(1), 256, 0, stream>>>(poolpart, fcw, fcb, mmdpart, dout);
}